// Round 1
// baseline (242.965 us; speedup 1.0000x reference)
//
#include <hip/hip_runtime.h>
#include <hip/hip_bf16.h>
#include <cstddef>

#define NB 4
#define NN 128
#define FF 128

// swizzled LDS index for the 128x128 edge tile: 16B block index XORed with
// a row hash so that the 8x8-register-tile reads (rows differing by 8) and
// the te-phase reads (rows differing by 1) both spread across banks.
__device__ __forceinline__ int xidx(int r, int kb) {
    return r * 128 + (((kb) ^ ((r ^ (r >> 3)) & 3)) << 2);
}

// ---------------------------------------------------------------------------
// prep: pack te1_w|te2_w|te3_w into a [128][32] padded matrix
// ---------------------------------------------------------------------------
__global__ void prep_te(const float* __restrict__ te1_w,
                        const float* __restrict__ te2_w,
                        const float* __restrict__ te3_w,
                        float* __restrict__ TE32) {
    int idx = blockIdx.x * 256 + threadIdx.x;   // 128*32 = 4096
    if (idx < 4096) {
        int k = idx >> 5, c = idx & 31;
        float v = 0.0f;
        if (c < 8)       v = te1_w[k * 8 + c];
        else if (c < 16) v = te2_w[k * 8 + (c - 8)];
        else if (c < 24) v = te3_w[k * 8 + (c - 16)];
        TE32[idx] = v;
    }
}

// ---------------------------------------------------------------------------
// node kernel: per (b,n) compute
//   M1  = z@m1_w + m1_b + graph@mg_w + mg_b        (msg_1 + msg_g folded)
//   M2  = z@m2_w + m2_b
//   O1z = z@o1_w + o1_b
//   T1v = z@t1_w + t1_b                            (== tri_1 == tri_3)
//   TT2 = z@t2_w + t2_b + graph@tg_w + tg_b        (tri_2 + tri_g folded)
// ---------------------------------------------------------------------------
__global__ __launch_bounds__(128)
void node_kernel(const float* __restrict__ node_fts, const float* __restrict__ hidden,
                 const float* __restrict__ graph_fts,
                 const float* __restrict__ m1_w, const float* __restrict__ m1_b,
                 const float* __restrict__ m2_w, const float* __restrict__ m2_b,
                 const float* __restrict__ mg_w, const float* __restrict__ mg_b,
                 const float* __restrict__ o1_w, const float* __restrict__ o1_b,
                 const float* __restrict__ t1_w, const float* __restrict__ t1_b,
                 const float* __restrict__ t2_w, const float* __restrict__ t2_b,
                 const float* __restrict__ tg_w, const float* __restrict__ tg_b,
                 float* __restrict__ M1, float* __restrict__ M2, float* __restrict__ O1z,
                 float* __restrict__ T1v, float* __restrict__ TT2) {
    __shared__ float zs[256];
    __shared__ float gs[128];
    const int b = blockIdx.x >> 7, n = blockIdx.x & 127;
    const int h = threadIdx.x;
    const size_t nb = (size_t)(b * 128 + n);
    zs[h]       = node_fts[nb * 128 + h];
    zs[128 + h] = hidden[nb * 128 + h];
    gs[h]       = graph_fts[b * 128 + h];
    __syncthreads();

    float a1 = m1_b[h] + mg_b[h];
    float a2 = m2_b[h];
    float a3 = o1_b[h];
    #pragma unroll 4
    for (int k = 0; k < 256; k++) {
        float z = zs[k];
        a1 = fmaf(z, m1_w[k * 128 + h], a1);
        a2 = fmaf(z, m2_w[k * 128 + h], a2);
        a3 = fmaf(z, o1_w[k * 128 + h], a3);
    }
    #pragma unroll 4
    for (int k = 0; k < 128; k++) a1 = fmaf(gs[k], mg_w[k * 128 + h], a1);
    M1[nb * 128 + h]  = a1;
    M2[nb * 128 + h]  = a2;
    O1z[nb * 128 + h] = a3;

    if (h < 8) {
        float t1 = t1_b[h];
        float t2 = t2_b[h] + tg_b[h];
        for (int k = 0; k < 256; k++) {
            t1 = fmaf(zs[k], t1_w[k * 8 + h], t1);
            t2 = fmaf(zs[k], t2_w[k * 8 + h], t2);
        }
        for (int k = 0; k < 128; k++) t2 = fmaf(gs[k], tg_w[k * 8 + h], t2);
        T1v[nb * 8 + h] = t1;
        TT2[nb * 8 + h] = t2;
    }
}

// ---------------------------------------------------------------------------
// edge kernel: one block = 128 edges (fixed b, i; rows r = j).
// X (LDS, swizzled) holds the 128x128 activation tile, updated in place
// through 3 GEMM stages. 8x8 register tile per thread.
// ---------------------------------------------------------------------------
__device__ __forceinline__ void mm_tile(const float* __restrict__ Wg,
                                        float* X, float* Wb,
                                        float acc[8][8], int tid, int ht, int rg) {
    const int h0 = ht * 8;
    for (int kt = 0; kt < 8; ++kt) {
        const float4* src = reinterpret_cast<const float4*>(Wg + kt * 2048);
        float4 w0 = src[tid];
        float4 w1 = src[tid + 256];
        __syncthreads();                       // previous Wb tile fully consumed
        reinterpret_cast<float4*>(Wb)[tid] = w0;
        reinterpret_cast<float4*>(Wb)[tid + 256] = w1;
        __syncthreads();
        #pragma unroll
        for (int k4 = 0; k4 < 4; ++k4) {
            const int kb = kt * 4 + k4;        // global 16B-block column index
            float xr[8][4];
            #pragma unroll
            for (int rr = 0; rr < 8; ++rr) {
                const int r = rg * 8 + rr;
                const float4 xv = *reinterpret_cast<const float4*>(&X[xidx(r, kb)]);
                xr[rr][0] = xv.x; xr[rr][1] = xv.y; xr[rr][2] = xv.z; xr[rr][3] = xv.w;
            }
            #pragma unroll
            for (int q = 0; q < 4; ++q) {
                const int kl = k4 * 4 + q;
                const float4 wa = *reinterpret_cast<const float4*>(&Wb[kl * 128 + h0]);
                const float4 wb = *reinterpret_cast<const float4*>(&Wb[kl * 128 + h0 + 4]);
                const float wv[8] = {wa.x, wa.y, wa.z, wa.w, wb.x, wb.y, wb.z, wb.w};
                #pragma unroll
                for (int rr = 0; rr < 8; ++rr)
                    #pragma unroll
                    for (int c = 0; c < 8; ++c)
                        acc[rr][c] = fmaf(xr[rr][q], wv[c], acc[rr][c]);
            }
        }
    }
}

__global__ __launch_bounds__(256, 2)
void edge_kernel(const float* __restrict__ edge_fts,
                 const float* __restrict__ me_w,   const float* __restrict__ me_b,
                 const float* __restrict__ mlp1_w, const float* __restrict__ mlp1_b,
                 const float* __restrict__ mlp2_w, const float* __restrict__ mlp2_b,
                 const float* __restrict__ TE32,
                 const float* __restrict__ te1_b, const float* __restrict__ te2_b,
                 const float* __restrict__ te3_b,
                 const float* __restrict__ M1,  const float* __restrict__ M2,
                 const float* __restrict__ T1v, const float* __restrict__ TT2,
                 float* __restrict__ msgs, float* __restrict__ T1buf,
                 float* __restrict__ T2buf, float* __restrict__ E3buf) {
    __shared__ __align__(16) float X[16384];   // 64 KB
    __shared__ __align__(16) float Wb[2048];   // 8 KB
    const int tid = threadIdx.x;
    const int b  = blockIdx.x >> 7;
    const int ie = blockIdx.x & 127;
    const int ht = tid & 15;
    const int rg = tid >> 4;
    const int h0 = ht * 8;

    // ---- stage 0: load edge rows into swizzled X ----
    const float4* esrc = reinterpret_cast<const float4*>(edge_fts + (size_t)(b * 128 + ie) * 16384);
    #pragma unroll
    for (int p = 0; p < 16; p++) {
        int f4 = tid + p * 256;
        int r = f4 >> 5, kb = f4 & 31;
        float4 v = esrc[f4];
        *reinterpret_cast<float4*>(&X[xidx(r, kb)]) = v;
    }
    __syncthreads();

    // ---- triplet-edge projections (read original X): 128 -> 32 (padded 24) ----
    {
        const int th2 = tid & 3;     // column block: c0 = th2*8 (th2==3 -> padding)
        const int rg2 = tid >> 2;    // rows rg2 and rg2+64
        const int c0 = th2 * 8;
        float acc2[2][8];
        #pragma unroll
        for (int rr = 0; rr < 2; rr++)
            #pragma unroll
            for (int t = 0; t < 8; t++) acc2[rr][t] = 0.0f;
        for (int kb = 0; kb < 32; kb++) {
            float wv2[4][8];
            #pragma unroll
            for (int q = 0; q < 4; q++) {
                const float* wp = TE32 + (kb * 4 + q) * 32 + c0;
                const float4 wa = *reinterpret_cast<const float4*>(wp);
                const float4 wbv = *reinterpret_cast<const float4*>(wp + 4);
                wv2[q][0] = wa.x; wv2[q][1] = wa.y; wv2[q][2] = wa.z; wv2[q][3] = wa.w;
                wv2[q][4] = wbv.x; wv2[q][5] = wbv.y; wv2[q][6] = wbv.z; wv2[q][7] = wbv.w;
            }
            #pragma unroll
            for (int rr = 0; rr < 2; rr++) {
                const int r = rg2 + rr * 64;
                const float4 xv = *reinterpret_cast<const float4*>(&X[xidx(r, kb)]);
                const float xa[4] = {xv.x, xv.y, xv.z, xv.w};
                #pragma unroll
                for (int q = 0; q < 4; q++)
                    #pragma unroll
                    for (int t = 0; t < 8; t++)
                        acc2[rr][t] = fmaf(xa[q], wv2[q][t], acc2[rr][t]);
            }
        }
        // epilogue: scatter into T1buf / T2buf / E3buf
        if (th2 == 0) {            // tri_e_1: T1buf[b][j=r][i=ie][t] = te1 + tri_1[b,i? no: +T1v[b,ie]]
            #pragma unroll
            for (int rr = 0; rr < 2; rr++) {
                const int r = rg2 + rr * 64;
                const float* tv = T1v + (size_t)(b * 128 + ie) * 8;
                float o[8];
                #pragma unroll
                for (int t = 0; t < 8; t++) o[t] = acc2[rr][t] + te1_b[t] + tv[t];
                float* dst = T1buf + ((size_t)(b * 128 + r) * 128 + ie) * 8;
                *reinterpret_cast<float4*>(dst)     = make_float4(o[0], o[1], o[2], o[3]);
                *reinterpret_cast<float4*>(dst + 4) = make_float4(o[4], o[5], o[6], o[7]);
            }
        } else if (th2 == 1) {     // tri_e_2: T2buf[b][i=ie][k=r][t]
            #pragma unroll
            for (int rr = 0; rr < 2; rr++) {
                const int r = rg2 + rr * 64;
                float o[8];
                #pragma unroll
                for (int t = 0; t < 8; t++) o[t] = acc2[rr][t] + te2_b[t];
                float* dst = T2buf + ((size_t)(b * 128 + ie) * 128 + r) * 8;
                *reinterpret_cast<float4*>(dst)     = make_float4(o[0], o[1], o[2], o[3]);
                *reinterpret_cast<float4*>(dst + 4) = make_float4(o[4], o[5], o[6], o[7]);
            }
        } else if (th2 == 2) {     // tri_e_3 + tri_2[b,jf=ie] + tri_g + tri_3[b,kf=r]
            #pragma unroll
            for (int rr = 0; rr < 2; rr++) {
                const int r = rg2 + rr * 64;
                const float* t2v = TT2 + (size_t)(b * 128 + ie) * 8;
                const float* t3v = T1v + (size_t)(b * 128 + r) * 8;
                float o[8];
                #pragma unroll
                for (int t = 0; t < 8; t++) o[t] = acc2[rr][t] + te3_b[t] + t2v[t] + t3v[t];
                float* dst = E3buf + ((size_t)(b * 128 + ie) * 128 + r) * 8;
                *reinterpret_cast<float4*>(dst)     = make_float4(o[0], o[1], o[2], o[3]);
                *reinterpret_cast<float4*>(dst + 4) = make_float4(o[4], o[5], o[6], o[7]);
            }
        }
    }

    float acc[8][8];

    // ---- stage 1: me_w + (me_b + M1[b,j] + M2[b,i]) , relu ----
    #pragma unroll
    for (int rr = 0; rr < 8; rr++)
        #pragma unroll
        for (int c = 0; c < 8; c++) acc[rr][c] = 0.0f;
    mm_tile(me_w, X, Wb, acc, tid, ht, rg);
    {
        float bcol[8];
        {
            const float4 e0 = *reinterpret_cast<const float4*>(me_b + h0);
            const float4 e1 = *reinterpret_cast<const float4*>(me_b + h0 + 4);
            const float* m2p = M2 + (size_t)(b * 128 + ie) * 128 + h0;
            const float4 q0 = *reinterpret_cast<const float4*>(m2p);
            const float4 q1 = *reinterpret_cast<const float4*>(m2p + 4);
            bcol[0] = e0.x + q0.x; bcol[1] = e0.y + q0.y; bcol[2] = e0.z + q0.z; bcol[3] = e0.w + q0.w;
            bcol[4] = e1.x + q1.x; bcol[5] = e1.y + q1.y; bcol[6] = e1.z + q1.z; bcol[7] = e1.w + q1.w;
        }
        __syncthreads();   // all stage-1 reads of X done
        #pragma unroll
        for (int rr = 0; rr < 8; rr++) {
            const int r = rg * 8 + rr;
            const float* m1p = M1 + (size_t)(b * 128 + r) * 128 + h0;
            const float4 a0 = *reinterpret_cast<const float4*>(m1p);
            const float4 a1 = *reinterpret_cast<const float4*>(m1p + 4);
            const float ad[8] = {a0.x, a0.y, a0.z, a0.w, a1.x, a1.y, a1.z, a1.w};
            float v[8];
            #pragma unroll
            for (int c = 0; c < 8; c++) v[c] = fmaxf(acc[rr][c] + bcol[c] + ad[c], 0.0f);
            *reinterpret_cast<float4*>(&X[xidx(r, 2 * ht)])     = make_float4(v[0], v[1], v[2], v[3]);
            *reinterpret_cast<float4*>(&X[xidx(r, 2 * ht + 1)]) = make_float4(v[4], v[5], v[6], v[7]);
        }
        __syncthreads();
    }

    // ---- stage 2: mlp1 + bias, relu ----
    #pragma unroll
    for (int rr = 0; rr < 8; rr++)
        #pragma unroll
        for (int c = 0; c < 8; c++) acc[rr][c] = 0.0f;
    mm_tile(mlp1_w, X, Wb, acc, tid, ht, rg);
    {
        const float4 e0 = *reinterpret_cast<const float4*>(mlp1_b + h0);
        const float4 e1 = *reinterpret_cast<const float4*>(mlp1_b + h0 + 4);
        const float bb[8] = {e0.x, e0.y, e0.z, e0.w, e1.x, e1.y, e1.z, e1.w};
        __syncthreads();
        #pragma unroll
        for (int rr = 0; rr < 8; rr++) {
            const int r = rg * 8 + rr;
            float v[8];
            #pragma unroll
            for (int c = 0; c < 8; c++) v[c] = fmaxf(acc[rr][c] + bb[c], 0.0f);
            *reinterpret_cast<float4*>(&X[xidx(r, 2 * ht)])     = make_float4(v[0], v[1], v[2], v[3]);
            *reinterpret_cast<float4*>(&X[xidx(r, 2 * ht + 1)]) = make_float4(v[4], v[5], v[6], v[7]);
        }
        __syncthreads();
    }

    // ---- stage 3: mlp2 + bias -> msgs ----
    #pragma unroll
    for (int rr = 0; rr < 8; rr++)
        #pragma unroll
        for (int c = 0; c < 8; c++) acc[rr][c] = 0.0f;
    mm_tile(mlp2_w, X, Wb, acc, tid, ht, rg);
    {
        const float4 e0 = *reinterpret_cast<const float4*>(mlp2_b + h0);
        const float4 e1 = *reinterpret_cast<const float4*>(mlp2_b + h0 + 4);
        const float bb[8] = {e0.x, e0.y, e0.z, e0.w, e1.x, e1.y, e1.z, e1.w};
        #pragma unroll
        for (int rr = 0; rr < 8; rr++) {
            const int r = rg * 8 + rr;
            float* dst = msgs + ((size_t)blockIdx.x * 128 + r) * 128 + h0;
            *reinterpret_cast<float4*>(dst) =
                make_float4(acc[rr][0] + bb[0], acc[rr][1] + bb[1], acc[rr][2] + bb[2], acc[rr][3] + bb[3]);
            *reinterpret_cast<float4*>(dst + 4) =
                make_float4(acc[rr][4] + bb[4], acc[rr][5] + bb[5], acc[rr][6] + bb[6], acc[rr][7] + bb[7]);
        }
    }
}

// ---------------------------------------------------------------------------
// masked max aggregation over i + output head: out = LN(relu(O1z + agg@o2_w + o2_b))
// ---------------------------------------------------------------------------
__global__ __launch_bounds__(128)
void agg_out_kernel(const float* __restrict__ msgs, const int* __restrict__ adj,
                    const float* __restrict__ O1z,
                    const float* __restrict__ o2_w, const float* __restrict__ o2_b,
                    const float* __restrict__ scale, const float* __restrict__ bias,
                    float* __restrict__ out) {
    __shared__ float aggs[128];
    __shared__ float red[2][2];
    const int b = blockIdx.x >> 7, j = blockIdx.x & 127;
    const int h = threadIdx.x;
    const float* mbase = msgs + (size_t)b * 2097152 + (size_t)j * 128 + h;
    const int* abase = adj + b * 16384 + j;
    float acc = -1e9f;
    #pragma unroll 4
    for (int i = 0; i < 128; i++) {
        float m = mbase[(size_t)i * 16384];
        int a = abase[i * 128];
        acc = fmaxf(acc, (a == 1) ? m : -1e9f);
    }
    aggs[h] = acc;
    __syncthreads();
    float val = o2_b[h] + O1z[(size_t)(b * 128 + j) * 128 + h];
    #pragma unroll 4
    for (int k = 0; k < 128; k++) val = fmaf(aggs[k], o2_w[k * 128 + h], val);
    float v = fmaxf(val, 0.0f);
    float s = v, s2 = v * v;
    #pragma unroll
    for (int off = 32; off >= 1; off >>= 1) {
        s += __shfl_down(s, off, 64);
        s2 += __shfl_down(s2, off, 64);
    }
    const int w = h >> 6;
    if ((h & 63) == 0) { red[w][0] = s; red[w][1] = s2; }
    __syncthreads();
    const float tot = red[0][0] + red[1][0];
    const float tot2 = red[0][1] + red[1][1];
    const float mean = tot * (1.0f / 128.0f);
    const float var = tot2 * (1.0f / 128.0f) - mean * mean;
    const float rstd = rsqrtf(var + 1e-5f);
    out[(size_t)(b * 128 + j) * 128 + h] = (v - mean) * rstd * scale[h] + bias[h];
}

// ---------------------------------------------------------------------------
// triplet kernel: per (b,jf) block -> 128 kf rows of tri_msgs
//   m8[kf][t] = max_i (T1[b,jf,i,t] + T2[b,i,kf,t]) + E3[b,jf,kf,t]
//   tri = LN(relu(m8 @ o3_w + o3_b))
// ---------------------------------------------------------------------------
__global__ __launch_bounds__(256)
void tri_kernel(const float* __restrict__ T1buf, const float* __restrict__ T2buf,
                const float* __restrict__ E3buf, const float* __restrict__ o3_w,
                const float* __restrict__ o3_b, const float* __restrict__ scale,
                const float* __restrict__ bias, float* __restrict__ tri_out) {
    __shared__ __align__(16) float T1s[1024];
    __shared__ __align__(16) float E3s[1024];
    __shared__ __align__(16) float o3s[1024];
    __shared__ __align__(16) float Ps[2][128][8];
    __shared__ float red[4][2];
    const int b = blockIdx.x >> 7, jf = blockIdx.x & 127;
    const int tid = threadIdx.x;
    {
        const float4* s1 = reinterpret_cast<const float4*>(T1buf + (size_t)(b * 128 + jf) * 1024);
        const float4* s3 = reinterpret_cast<const float4*>(E3buf + (size_t)(b * 128 + jf) * 1024);
        const float4* sw = reinterpret_cast<const float4*>(o3_w);
        reinterpret_cast<float4*>(T1s)[tid] = s1[tid];
        reinterpret_cast<float4*>(E3s)[tid] = s3[tid];
        reinterpret_cast<float4*>(o3s)[tid] = sw[tid];
    }
    __syncthreads();

    const int kf = tid & 127, ihalf = tid >> 7;
    float a8[8];
    #pragma unroll
    for (int t = 0; t < 8; t++) a8[t] = -1e30f;
    const float4* t2p = reinterpret_cast<const float4*>(T2buf + (size_t)b * 131072);
    for (int ii = 0; ii < 64; ++ii) {
        const int i = ihalf * 64 + ii;
        const float4 p = t2p[(i * 128 + kf) * 2];
        const float4 q = t2p[(i * 128 + kf) * 2 + 1];
        const float* t1r = &T1s[i * 8];
        a8[0] = fmaxf(a8[0], t1r[0] + p.x);
        a8[1] = fmaxf(a8[1], t1r[1] + p.y);
        a8[2] = fmaxf(a8[2], t1r[2] + p.z);
        a8[3] = fmaxf(a8[3], t1r[3] + p.w);
        a8[4] = fmaxf(a8[4], t1r[4] + q.x);
        a8[5] = fmaxf(a8[5], t1r[5] + q.y);
        a8[6] = fmaxf(a8[6], t1r[6] + q.z);
        a8[7] = fmaxf(a8[7], t1r[7] + q.w);
    }
    #pragma unroll
    for (int t = 0; t < 8; t++) Ps[ihalf][kf][t] = a8[t];
    __syncthreads();

    const int g = tid >> 7;
    const int h = tid & 127;
    for (int kk = 0; kk < 64; ++kk) {
        const int kfx = kk * 2 + g;
        float m8[8];
        #pragma unroll
        for (int t = 0; t < 8; t++)
            m8[t] = fmaxf(Ps[0][kfx][t], Ps[1][kfx][t]) + E3s[kfx * 8 + t];
        float val = o3_b[h];
        #pragma unroll
        for (int t = 0; t < 8; t++) val = fmaf(m8[t], o3s[t * 128 + h], val);
        float v = fmaxf(val, 0.0f);
        float s = v, s2 = v * v;
        #pragma unroll
        for (int off = 32; off >= 1; off >>= 1) {
            s += __shfl_down(s, off, 64);
            s2 += __shfl_down(s2, off, 64);
        }
        const int w = tid >> 6;
        if ((tid & 63) == 0) { red[w][0] = s; red[w][1] = s2; }
        __syncthreads();
        const float tot = red[2 * g][0] + red[2 * g + 1][0];
        const float tot2 = red[2 * g][1] + red[2 * g + 1][1];
        const float mean = tot * (1.0f / 128.0f);
        const float var = tot2 * (1.0f / 128.0f) - mean * mean;
        const float rstd = rsqrtf(var + 1e-5f);
        tri_out[(size_t)((b * 128 + jf) * 128 + kfx) * 128 + h] =
            (v - mean) * rstd * scale[h] + bias[h];
        __syncthreads();
    }
}

// ---------------------------------------------------------------------------
extern "C" void kernel_launch(void* const* d_in, const int* in_sizes, int n_in,
                              void* d_out, int out_size, void* d_ws, size_t ws_size,
                              hipStream_t stream) {
    const float* node_fts  = (const float*)d_in[0];
    const float* edge_fts  = (const float*)d_in[1];
    const float* graph_fts = (const float*)d_in[2];
    const float* hidden    = (const float*)d_in[3];
    const int*   adj       = (const int*)d_in[4];
    const float* m1_w = (const float*)d_in[5],  *m1_b = (const float*)d_in[6];
    const float* m2_w = (const float*)d_in[7],  *m2_b = (const float*)d_in[8];
    const float* me_w = (const float*)d_in[9],  *me_b = (const float*)d_in[10];
    const float* mg_w = (const float*)d_in[11], *mg_b = (const float*)d_in[12];
    const float* mlp1_w = (const float*)d_in[13], *mlp1_b = (const float*)d_in[14];
    const float* mlp2_w = (const float*)d_in[15], *mlp2_b = (const float*)d_in[16];
    const float* o1_w = (const float*)d_in[17], *o1_b = (const float*)d_in[18];
    const float* o2_w = (const float*)d_in[19], *o2_b = (const float*)d_in[20];
    const float* t1_w = (const float*)d_in[21], *t1_b = (const float*)d_in[22];
    const float* t2_w = (const float*)d_in[23], *t2_b = (const float*)d_in[24];
    const float* te1_w = (const float*)d_in[25], *te1_b = (const float*)d_in[26];
    const float* te2_w = (const float*)d_in[27], *te2_b = (const float*)d_in[28];
    const float* te3_w = (const float*)d_in[29], *te3_b = (const float*)d_in[30];
    const float* tg_w = (const float*)d_in[31], *tg_b = (const float*)d_in[32];
    const float* o3_w = (const float*)d_in[33], *o3_b = (const float*)d_in[34];
    const float* norm_scale = (const float*)d_in[35];
    const float* norm_bias  = (const float*)d_in[36];

    float* ws = (float*)d_ws;
    float* M1    = ws;                 // 65536
    float* M2    = ws + 65536;         // 65536
    float* O1z   = ws + 131072;        // 65536
    float* T1v   = ws + 196608;        // 4096
    float* TT2   = ws + 200704;        // 4096
    float* TE32  = ws + 204800;        // 4096
    float* msgs  = ws + 208896;        // 8388608
    float* T1buf = ws + 8597504;       // 524288
    float* T2buf = ws + 9121792;       // 524288
    float* E3buf = ws + 9646080;       // 524288  (total 10170368 floats ~ 40.7 MB)

    float* out_p  = (float*)d_out;            // [4,128,128]
    float* tri_p  = (float*)d_out + 65536;    // [4,128,128,128]

    prep_te<<<16, 256, 0, stream>>>(te1_w, te2_w, te3_w, TE32);
    node_kernel<<<512, 128, 0, stream>>>(node_fts, hidden, graph_fts,
                                         m1_w, m1_b, m2_w, m2_b, mg_w, mg_b,
                                         o1_w, o1_b, t1_w, t1_b, t2_w, t2_b,
                                         tg_w, tg_b, M1, M2, O1z, T1v, TT2);
    edge_kernel<<<512, 256, 0, stream>>>(edge_fts, me_w, me_b, mlp1_w, mlp1_b,
                                         mlp2_w, mlp2_b, TE32, te1_b, te2_b, te3_b,
                                         M1, M2, T1v, TT2, msgs, T1buf, T2buf, E3buf);
    agg_out_kernel<<<512, 128, 0, stream>>>(msgs, adj, O1z, o2_w, o2_b,
                                            norm_scale, norm_bias, out_p);
    tri_kernel<<<512, 256, 0, stream>>>(T1buf, T2buf, E3buf, o3_w, o3_b,
                                        norm_scale, norm_bias, tri_p);
}

// Round 2
// 145.542 us; speedup vs baseline: 1.6694x; 1.6694x over previous
//
#include <hip/hip_runtime.h>
#include <hip/hip_bf16.h>
#include <cstddef>
#include <cstdint>

typedef __attribute__((ext_vector_type(8))) short bf16x8;
typedef __attribute__((ext_vector_type(4))) float f32x4;
typedef unsigned short ushort_t;

__device__ __forceinline__ ushort_t f2b(float f) {
    uint32_t x = __float_as_uint(f);
    uint32_t r = (x + 0x7FFFu + ((x >> 16) & 1u)) >> 16;   // RNE
    return (ushort_t)r;
}
__device__ __forceinline__ float b2f(ushort_t u) {
    return __uint_as_float(((uint32_t)u) << 16);
}

// ---------------------------------------------------------------------------
// prep: bf16-transpose the edge-chain weights Wt[o][h] = W[h][o], and pack
// te1|te2|te3 into TEt[32][128] bf16 (o-major, padded to 32).
// ---------------------------------------------------------------------------
__global__ void prep_kernel(const float* __restrict__ me_w, const float* __restrict__ mlp1_w,
                            const float* __restrict__ mlp2_w,
                            const float* __restrict__ te1_w, const float* __restrict__ te2_w,
                            const float* __restrict__ te3_w,
                            ushort_t* __restrict__ Wme, ushort_t* __restrict__ Wm1,
                            ushort_t* __restrict__ Wm2, ushort_t* __restrict__ TEt) {
    int idx = blockIdx.x * 256 + threadIdx.x;
    if (idx < 16384) {
        int o = idx >> 7, h = idx & 127;
        Wme[idx] = f2b(me_w[h * 128 + o]);
    } else if (idx < 32768) {
        int t = idx - 16384, o = t >> 7, h = t & 127;
        Wm1[t] = f2b(mlp1_w[h * 128 + o]);
    } else if (idx < 49152) {
        int t = idx - 32768, o = t >> 7, h = t & 127;
        Wm2[t] = f2b(mlp2_w[h * 128 + o]);
    } else if (idx < 53248) {
        int t = idx - 49152, c = t >> 7, h = t & 127;
        float v = 0.0f;
        if (c < 8)       v = te1_w[h * 8 + c];
        else if (c < 16) v = te2_w[h * 8 + (c - 8)];
        else if (c < 24) v = te3_w[h * 8 + (c - 16)];
        TEt[t] = f2b(v);
    }
}

// ---------------------------------------------------------------------------
// node kernel (fp32, unchanged math): M1 = z@m1_w+m1_b+g@mg_w+mg_b,
// M2 = z@m2_w+m2_b, O1z = z@o1_w+o1_b, T1v = z@t1_w+t1_b, TT2 = z@t2_w+t2_b+g@tg_w+tg_b
// ---------------------------------------------------------------------------
__global__ __launch_bounds__(128)
void node_kernel(const float* __restrict__ node_fts, const float* __restrict__ hidden,
                 const float* __restrict__ graph_fts,
                 const float* __restrict__ m1_w, const float* __restrict__ m1_b,
                 const float* __restrict__ m2_w, const float* __restrict__ m2_b,
                 const float* __restrict__ mg_w, const float* __restrict__ mg_b,
                 const float* __restrict__ o1_w, const float* __restrict__ o1_b,
                 const float* __restrict__ t1_w, const float* __restrict__ t1_b,
                 const float* __restrict__ t2_w, const float* __restrict__ t2_b,
                 const float* __restrict__ tg_w, const float* __restrict__ tg_b,
                 float* __restrict__ M1, float* __restrict__ M2, float* __restrict__ O1z,
                 float* __restrict__ T1v, float* __restrict__ TT2) {
    __shared__ float zs[256];
    __shared__ float gs[128];
    const int b = blockIdx.x >> 7, n = blockIdx.x & 127;
    const int h = threadIdx.x;
    const size_t nb = (size_t)(b * 128 + n);
    zs[h]       = node_fts[nb * 128 + h];
    zs[128 + h] = hidden[nb * 128 + h];
    gs[h]       = graph_fts[b * 128 + h];
    __syncthreads();

    float a1 = m1_b[h] + mg_b[h];
    float a2 = m2_b[h];
    float a3 = o1_b[h];
    #pragma unroll 4
    for (int k = 0; k < 256; k++) {
        float z = zs[k];
        a1 = fmaf(z, m1_w[k * 128 + h], a1);
        a2 = fmaf(z, m2_w[k * 128 + h], a2);
        a3 = fmaf(z, o1_w[k * 128 + h], a3);
    }
    #pragma unroll 4
    for (int k = 0; k < 128; k++) a1 = fmaf(gs[k], mg_w[k * 128 + h], a1);
    M1[nb * 128 + h]  = a1;
    M2[nb * 128 + h]  = a2;
    O1z[nb * 128 + h] = a3;

    if (h < 8) {
        float t1 = t1_b[h];
        float t2 = t2_b[h] + tg_b[h];
        for (int k = 0; k < 256; k++) {
            t1 = fmaf(zs[k], t1_w[k * 8 + h], t1);
            t2 = fmaf(zs[k], t2_w[k * 8 + h], t2);
        }
        for (int k = 0; k < 128; k++) t2 = fmaf(gs[k], tg_w[k * 8 + h], t2);
        T1v[nb * 8 + h] = t1;
        TT2[nb * 8 + h] = t2;
    }
}

// ---------------------------------------------------------------------------
// edge kernel, MFMA bf16. One block = (b, ie), 128x128 tile (rows j, feat h).
// X in LDS bf16, chunk-XOR-swizzled. Swapped operands: A = Wt[o][h] (global,
// L2-hot), B = X[j][h] (LDS). D: lane holds fixed j, 4 consecutive o ->
// contiguous 8B LDS write-back.  Wave w: o-block (w&1)*64, j-block (w>>1)*64.
// ---------------------------------------------------------------------------
__device__ __forceinline__ void mm128(const ushort_t* __restrict__ Wt, const char* Xb,
                                      f32x4 acc[4][4], int o_blk, int j_blk, int g, int lq) {
    #pragma unroll
    for (int ks = 0; ks < 4; ks++) {
        bf16x8 a[4], bb[4];
        #pragma unroll
        for (int m = 0; m < 4; m++)
            a[m] = *reinterpret_cast<const bf16x8*>(Wt + (size_t)(o_blk + m * 16 + lq) * 128 + ks * 32 + g * 8);
        #pragma unroll
        for (int n = 0; n < 4; n++) {
            int j = j_blk + n * 16 + lq;
            bb[n] = *reinterpret_cast<const bf16x8*>(Xb + j * 256 + (((ks * 4 + g) ^ (j & 7)) << 4));
        }
        #pragma unroll
        for (int m = 0; m < 4; m++)
            #pragma unroll
            for (int n = 0; n < 4; n++)
                acc[m][n] = __builtin_amdgcn_mfma_f32_16x16x32_bf16(a[m], bb[n], acc[m][n], 0, 0, 0);
    }
}

__global__ __launch_bounds__(256, 2)
void edge_kernel(const float* __restrict__ edge_fts,
                 const ushort_t* __restrict__ Wme, const float* __restrict__ me_b,
                 const ushort_t* __restrict__ Wm1, const float* __restrict__ mlp1_b,
                 const ushort_t* __restrict__ Wm2, const float* __restrict__ mlp2_b,
                 const ushort_t* __restrict__ TEt,
                 const float* __restrict__ te1_b, const float* __restrict__ te2_b,
                 const float* __restrict__ te3_b,
                 const float* __restrict__ M1,  const float* __restrict__ M2,
                 const float* __restrict__ T1v, const float* __restrict__ TT2,
                 ushort_t* __restrict__ msgsB, float* __restrict__ T1buf,
                 float* __restrict__ T2buf, float* __restrict__ E3buf) {
    __shared__ ushort_t Xs[16384];     // 32 KB bf16 tile, swizzled
    char* Xb = (char*)Xs;
    const int tid = threadIdx.x;
    const int b  = blockIdx.x >> 7;
    const int ie = blockIdx.x & 127;
    const int w = tid >> 6, l = tid & 63, g = l >> 4, lq = l & 15;
    const int o_blk = (w & 1) * 64, j_blk = (w >> 1) * 64;

    // ---- stage 0: global fp32 -> bf16 swizzled LDS ----
    const float4* esrc = reinterpret_cast<const float4*>(edge_fts + (size_t)(b * 128 + ie) * 16384);
    #pragma unroll
    for (int p = 0; p < 16; p++) {
        int idx = tid + p * 256;       // float4 index 0..4095
        int r = idx >> 5, c4 = idx & 31;
        float4 v = esrc[idx];
        uint2 pk;
        pk.x = (uint32_t)f2b(v.x) | ((uint32_t)f2b(v.y) << 16);
        pk.y = (uint32_t)f2b(v.z) | ((uint32_t)f2b(v.w) << 16);
        *reinterpret_cast<uint2*>(Xb + r * 256 + (((c4 >> 1) ^ (r & 7)) << 4) + (c4 & 1) * 8) = pk;
    }
    __syncthreads();

    // ---- te projections: A = TEt (32x128, wave takes m_te = w&1), B = X ----
    {
        const int m_te = w & 1;
        const ushort_t* At = TEt + m_te * 16 * 128;
        f32x4 acc[4];
        #pragma unroll
        for (int n = 0; n < 4; n++) acc[n] = (f32x4){0.f, 0.f, 0.f, 0.f};
        #pragma unroll
        for (int ks = 0; ks < 4; ks++) {
            bf16x8 a = *reinterpret_cast<const bf16x8*>(At + lq * 128 + ks * 32 + g * 8);
            #pragma unroll
            for (int n = 0; n < 4; n++) {
                int j = j_blk + n * 16 + lq;
                bf16x8 bbv = *reinterpret_cast<const bf16x8*>(Xb + j * 256 + (((ks * 4 + g) ^ (j & 7)) << 4));
                acc[n] = __builtin_amdgcn_mfma_f32_16x16x32_bf16(a, bbv, acc[n], 0, 0, 0);
            }
        }
        // epilogue: o = m_te*16 + g*4 + r
        if (m_te == 0) {
            if (g < 2) {   // te1: T1buf[b][j][ie][t]
                int t0 = g * 4;
                const float4 eb = *reinterpret_cast<const float4*>(te1_b + t0);
                const float4 tv = *reinterpret_cast<const float4*>(T1v + (size_t)(b * 128 + ie) * 8 + t0);
                #pragma unroll
                for (int n = 0; n < 4; n++) {
                    int j = j_blk + n * 16 + lq;
                    float4 o4 = make_float4(acc[n][0] + eb.x + tv.x, acc[n][1] + eb.y + tv.y,
                                            acc[n][2] + eb.z + tv.z, acc[n][3] + eb.w + tv.w);
                    *reinterpret_cast<float4*>(T1buf + ((size_t)(b * 128 + j) * 128 + ie) * 8 + t0) = o4;
                }
            } else {       // te2: T2buf[b][ie][j][t]
                int t0 = g * 4 - 8;
                const float4 eb = *reinterpret_cast<const float4*>(te2_b + t0);
                #pragma unroll
                for (int n = 0; n < 4; n++) {
                    int j = j_blk + n * 16 + lq;
                    float4 o4 = make_float4(acc[n][0] + eb.x, acc[n][1] + eb.y,
                                            acc[n][2] + eb.z, acc[n][3] + eb.w);
                    *reinterpret_cast<float4*>(T2buf + ((size_t)(b * 128 + ie) * 128 + j) * 8 + t0) = o4;
                }
            }
        } else if (g < 2) { // te3: E3buf[b][ie][j][t] + TT2[b,ie] + T1v[b,j]
            int t0 = g * 4;
            const float4 eb = *reinterpret_cast<const float4*>(te3_b + t0);
            const float4 t2v = *reinterpret_cast<const float4*>(TT2 + (size_t)(b * 128 + ie) * 8 + t0);
            #pragma unroll
            for (int n = 0; n < 4; n++) {
                int j = j_blk + n * 16 + lq;
                const float4 t3v = *reinterpret_cast<const float4*>(T1v + (size_t)(b * 128 + j) * 8 + t0);
                float4 o4 = make_float4(acc[n][0] + eb.x + t2v.x + t3v.x,
                                        acc[n][1] + eb.y + t2v.y + t3v.y,
                                        acc[n][2] + eb.z + t2v.z + t3v.z,
                                        acc[n][3] + eb.w + t2v.w + t3v.w);
                *reinterpret_cast<float4*>(E3buf + ((size_t)(b * 128 + ie) * 128 + j) * 8 + t0) = o4;
            }
        }
    }

    f32x4 acc[4][4];

    // ================= stage 1: X = relu(X@me_w + me_b + M1[b,j] + M2[b,ie]) =================
    #pragma unroll
    for (int m = 0; m < 4; m++)
        #pragma unroll
        for (int n = 0; n < 4; n++) acc[m][n] = (f32x4){0.f, 0.f, 0.f, 0.f};
    mm128(Wme, Xb, acc, o_blk, j_blk, g, lq);
    {
        float4 bc[4];
        #pragma unroll
        for (int m = 0; m < 4; m++) {
            int o0 = o_blk + m * 16 + g * 4;
            const float4 eb = *reinterpret_cast<const float4*>(me_b + o0);
            const float4 m2 = *reinterpret_cast<const float4*>(M2 + (size_t)(b * 128 + ie) * 128 + o0);
            bc[m] = make_float4(eb.x + m2.x, eb.y + m2.y, eb.z + m2.z, eb.w + m2.w);
        }
        __syncthreads();   // all waves done reading X (te + stage1)
        #pragma unroll
        for (int m = 0; m < 4; m++) {
            int o0 = o_blk + m * 16 + g * 4;
            #pragma unroll
            for (int n = 0; n < 4; n++) {
                int j = j_blk + n * 16 + lq;
                const float4 m1 = *reinterpret_cast<const float4*>(M1 + (size_t)(b * 128 + j) * 128 + o0);
                float r0 = fmaxf(acc[m][n][0] + bc[m].x + m1.x, 0.f);
                float r1 = fmaxf(acc[m][n][1] + bc[m].y + m1.y, 0.f);
                float r2 = fmaxf(acc[m][n][2] + bc[m].z + m1.z, 0.f);
                float r3 = fmaxf(acc[m][n][3] + bc[m].w + m1.w, 0.f);
                uint2 pk;
                pk.x = (uint32_t)f2b(r0) | ((uint32_t)f2b(r1) << 16);
                pk.y = (uint32_t)f2b(r2) | ((uint32_t)f2b(r3) << 16);
                *reinterpret_cast<uint2*>(Xb + j * 256 + ((((o0 >> 3) ^ (j & 7))) << 4) + (o0 & 7) * 2) = pk;
            }
        }
        __syncthreads();
    }

    // ================= stage 2: X = relu(X@mlp1_w + mlp1_b) =================
    #pragma unroll
    for (int m = 0; m < 4; m++)
        #pragma unroll
        for (int n = 0; n < 4; n++) acc[m][n] = (f32x4){0.f, 0.f, 0.f, 0.f};
    mm128(Wm1, Xb, acc, o_blk, j_blk, g, lq);
    {
        float4 bc[4];
        #pragma unroll
        for (int m = 0; m < 4; m++) {
            int o0 = o_blk + m * 16 + g * 4;
            bc[m] = *reinterpret_cast<const float4*>(mlp1_b + o0);
        }
        __syncthreads();
        #pragma unroll
        for (int m = 0; m < 4; m++) {
            int o0 = o_blk + m * 16 + g * 4;
            #pragma unroll
            for (int n = 0; n < 4; n++) {
                int j = j_blk + n * 16 + lq;
                float r0 = fmaxf(acc[m][n][0] + bc[m].x, 0.f);
                float r1 = fmaxf(acc[m][n][1] + bc[m].y, 0.f);
                float r2 = fmaxf(acc[m][n][2] + bc[m].z, 0.f);
                float r3 = fmaxf(acc[m][n][3] + bc[m].w, 0.f);
                uint2 pk;
                pk.x = (uint32_t)f2b(r0) | ((uint32_t)f2b(r1) << 16);
                pk.y = (uint32_t)f2b(r2) | ((uint32_t)f2b(r3) << 16);
                *reinterpret_cast<uint2*>(Xb + j * 256 + ((((o0 >> 3) ^ (j & 7))) << 4) + (o0 & 7) * 2) = pk;
            }
        }
        __syncthreads();
    }

    // ================= stage 3: msgs = X@mlp2_w + mlp2_b (no relu) =================
    #pragma unroll
    for (int m = 0; m < 4; m++)
        #pragma unroll
        for (int n = 0; n < 4; n++) acc[m][n] = (f32x4){0.f, 0.f, 0.f, 0.f};
    mm128(Wm2, Xb, acc, o_blk, j_blk, g, lq);
    {
        float4 bc[4];
        #pragma unroll
        for (int m = 0; m < 4; m++) {
            int o0 = o_blk + m * 16 + g * 4;
            bc[m] = *reinterpret_cast<const float4*>(mlp2_b + o0);
        }
        __syncthreads();
        #pragma unroll
        for (int m = 0; m < 4; m++) {
            int o0 = o_blk + m * 16 + g * 4;
            #pragma unroll
            for (int n = 0; n < 4; n++) {
                int j = j_blk + n * 16 + lq;
                float r0 = acc[m][n][0] + bc[m].x;
                float r1 = acc[m][n][1] + bc[m].y;
                float r2 = acc[m][n][2] + bc[m].z;
                float r3 = acc[m][n][3] + bc[m].w;
                uint2 pk;
                pk.x = (uint32_t)f2b(r0) | ((uint32_t)f2b(r1) << 16);
                pk.y = (uint32_t)f2b(r2) | ((uint32_t)f2b(r3) << 16);
                *reinterpret_cast<uint2*>(Xb + j * 256 + ((((o0 >> 3) ^ (j & 7))) << 4) + (o0 & 7) * 2) = pk;
            }
        }
        __syncthreads();
    }

    // ---- coalesced de-swizzle copy-out: msgsB[b][ie][j][h] bf16 ----
    {
        ushort_t* mdst = msgsB + (size_t)(b * 128 + ie) * 16384;
        const int r0 = tid >> 4, sc = tid & 15;
        #pragma unroll
        for (int q = 0; q < 8; q++) {
            int r = r0 + q * 16;
            uint4 v = *reinterpret_cast<const uint4*>(Xb + r * 256 + sc * 16);
            int logical = sc ^ (r & 7);
            *reinterpret_cast<uint4*>(mdst + r * 128 + logical * 8) = v;
        }
    }
}

// ---------------------------------------------------------------------------
// masked max aggregation over i + output head (msgs now bf16)
// ---------------------------------------------------------------------------
__global__ __launch_bounds__(128)
void agg_out_kernel(const ushort_t* __restrict__ msgsB, const int* __restrict__ adj,
                    const float* __restrict__ O1z,
                    const float* __restrict__ o2_w, const float* __restrict__ o2_b,
                    const float* __restrict__ scale, const float* __restrict__ bias,
                    float* __restrict__ out) {
    __shared__ float aggs[128];
    __shared__ float red[2][2];
    const int b = blockIdx.x >> 7, j = blockIdx.x & 127;
    const int h = threadIdx.x;
    const ushort_t* mbase = msgsB + (size_t)b * 2097152 + (size_t)j * 128 + h;
    const int* abase = adj + b * 16384 + j;
    float acc = -1e9f;
    #pragma unroll 4
    for (int i = 0; i < 128; i++) {
        float m = b2f(mbase[(size_t)i * 16384]);
        int a = abase[i * 128];
        acc = fmaxf(acc, (a == 1) ? m : -1e9f);
    }
    aggs[h] = acc;
    __syncthreads();
    float val = o2_b[h] + O1z[(size_t)(b * 128 + j) * 128 + h];
    #pragma unroll 4
    for (int k = 0; k < 128; k++) val = fmaf(aggs[k], o2_w[k * 128 + h], val);
    float v = fmaxf(val, 0.0f);
    float s = v, s2 = v * v;
    #pragma unroll
    for (int off = 32; off >= 1; off >>= 1) {
        s += __shfl_down(s, off, 64);
        s2 += __shfl_down(s2, off, 64);
    }
    const int w = h >> 6;
    if ((h & 63) == 0) { red[w][0] = s; red[w][1] = s2; }
    __syncthreads();
    const float tot = red[0][0] + red[1][0];
    const float tot2 = red[0][1] + red[1][1];
    const float mean = tot * (1.0f / 128.0f);
    const float var = tot2 * (1.0f / 128.0f) - mean * mean;
    const float rstd = rsqrtf(var + 1e-5f);
    out[(size_t)(b * 128 + j) * 128 + h] = (v - mean) * rstd * scale[h] + bias[h];
}

// ---------------------------------------------------------------------------
// triplet kernel: phase1 = max over i; phase2 = wave-per-row (no barriers)
// ---------------------------------------------------------------------------
__global__ __launch_bounds__(256)
void tri_kernel(const float* __restrict__ T1buf, const float* __restrict__ T2buf,
                const float* __restrict__ E3buf, const float* __restrict__ o3_w,
                const float* __restrict__ o3_b, const float* __restrict__ scale,
                const float* __restrict__ bias, float* __restrict__ tri_out) {
    __shared__ __align__(16) float T1s[1024];
    __shared__ __align__(16) float E3s[1024];
    __shared__ __align__(16) float o3s[1024];
    __shared__ __align__(16) float Ps[2][128][8];
    const int b = blockIdx.x >> 7, jf = blockIdx.x & 127;
    const int tid = threadIdx.x;
    {
        reinterpret_cast<float4*>(T1s)[tid] =
            reinterpret_cast<const float4*>(T1buf + (size_t)(b * 128 + jf) * 1024)[tid];
        reinterpret_cast<float4*>(E3s)[tid] =
            reinterpret_cast<const float4*>(E3buf + (size_t)(b * 128 + jf) * 1024)[tid];
        reinterpret_cast<float4*>(o3s)[tid] = reinterpret_cast<const float4*>(o3_w)[tid];
    }
    __syncthreads();

    {
        const int kf = tid & 127, ih = tid >> 7;
        float a8[8];
        #pragma unroll
        for (int t = 0; t < 8; t++) a8[t] = -3.0e38f;
        const float4* t2p = reinterpret_cast<const float4*>(T2buf + (size_t)b * 131072);
        #pragma unroll 2
        for (int ii = 0; ii < 64; ++ii) {
            const int i = ih * 64 + ii;
            const float4 p = t2p[(i * 128 + kf) * 2];
            const float4 q = t2p[(i * 128 + kf) * 2 + 1];
            const float* t1r = &T1s[i * 8];
            a8[0] = fmaxf(a8[0], t1r[0] + p.x);
            a8[1] = fmaxf(a8[1], t1r[1] + p.y);
            a8[2] = fmaxf(a8[2], t1r[2] + p.z);
            a8[3] = fmaxf(a8[3], t1r[3] + p.w);
            a8[4] = fmaxf(a8[4], t1r[4] + q.x);
            a8[5] = fmaxf(a8[5], t1r[5] + q.y);
            a8[6] = fmaxf(a8[6], t1r[6] + q.z);
            a8[7] = fmaxf(a8[7], t1r[7] + q.w);
        }
        #pragma unroll
        for (int t = 0; t < 8; t++) Ps[ih][kf][t] = a8[t];
    }
    __syncthreads();

    const int w = tid >> 6, l = tid & 63;
    const float ob0 = o3_b[l],     ob1 = o3_b[l + 64];
    const float sc0 = scale[l],    sc1 = scale[l + 64];
    const float bi0 = bias[l],     bi1 = bias[l + 64];
    for (int kk = 0; kk < 32; ++kk) {
        const int kf = w * 32 + kk;
        float m8[8];
        #pragma unroll
        for (int t = 0; t < 8; t++)
            m8[t] = fmaxf(Ps[0][kf][t], Ps[1][kf][t]) + E3s[kf * 8 + t];
        float v0 = ob0, v1 = ob1;
        #pragma unroll
        for (int t = 0; t < 8; t++) {
            v0 = fmaf(m8[t], o3s[t * 128 + l], v0);
            v1 = fmaf(m8[t], o3s[t * 128 + l + 64], v1);
        }
        v0 = fmaxf(v0, 0.0f);
        v1 = fmaxf(v1, 0.0f);
        float s = v0 + v1, s2 = v0 * v0 + v1 * v1;
        #pragma unroll
        for (int off = 32; off >= 1; off >>= 1) {
            s  += __shfl_xor(s, off, 64);
            s2 += __shfl_xor(s2, off, 64);
        }
        const float mean = s * (1.0f / 128.0f);
        const float var = s2 * (1.0f / 128.0f) - mean * mean;
        const float rstd = rsqrtf(var + 1e-5f);
        float* dst = tri_out + (size_t)((b * 128 + jf) * 128 + kf) * 128;
        dst[l]      = (v0 - mean) * rstd * sc0 + bi0;
        dst[l + 64] = (v1 - mean) * rstd * sc1 + bi1;
    }
}

// ---------------------------------------------------------------------------
extern "C" void kernel_launch(void* const* d_in, const int* in_sizes, int n_in,
                              void* d_out, int out_size, void* d_ws, size_t ws_size,
                              hipStream_t stream) {
    const float* node_fts  = (const float*)d_in[0];
    const float* edge_fts  = (const float*)d_in[1];
    const float* graph_fts = (const float*)d_in[2];
    const float* hidden    = (const float*)d_in[3];
    const int*   adj       = (const int*)d_in[4];
    const float* m1_w = (const float*)d_in[5],  *m1_b = (const float*)d_in[6];
    const float* m2_w = (const float*)d_in[7],  *m2_b = (const float*)d_in[8];
    const float* me_w = (const float*)d_in[9],  *me_b = (const float*)d_in[10];
    const float* mg_w = (const float*)d_in[11], *mg_b = (const float*)d_in[12];
    const float* mlp1_w = (const float*)d_in[13], *mlp1_b = (const float*)d_in[14];
    const float* mlp2_w = (const float*)d_in[15], *mlp2_b = (const float*)d_in[16];
    const float* o1_w = (const float*)d_in[17], *o1_b = (const float*)d_in[18];
    const float* o2_w = (const float*)d_in[19], *o2_b = (const float*)d_in[20];
    const float* t1_w = (const float*)d_in[21], *t1_b = (const float*)d_in[22];
    const float* t2_w = (const float*)d_in[23], *t2_b = (const float*)d_in[24];
    const float* te1_w = (const float*)d_in[25], *te1_b = (const float*)d_in[26];
    const float* te2_w = (const float*)d_in[27], *te2_b = (const float*)d_in[28];
    const float* te3_w = (const float*)d_in[29], *te3_b = (const float*)d_in[30];
    const float* tg_w = (const float*)d_in[31], *tg_b = (const float*)d_in[32];
    const float* o3_w = (const float*)d_in[33], *o3_b = (const float*)d_in[34];
    const float* norm_scale = (const float*)d_in[35];
    const float* norm_bias  = (const float*)d_in[36];

    char* w8 = (char*)d_ws;
    float*    M1    = (float*)(w8 + 0);          // 256 KB
    float*    M2    = (float*)(w8 + 262144);     // 256 KB
    float*    O1z   = (float*)(w8 + 524288);     // 256 KB
    float*    T1v   = (float*)(w8 + 786432);     // 16 KB
    float*    TT2   = (float*)(w8 + 802816);     // 16 KB
    ushort_t* Wme   = (ushort_t*)(w8 + 819200);  // 32 KB
    ushort_t* Wm1   = (ushort_t*)(w8 + 851968);  // 32 KB
    ushort_t* Wm2   = (ushort_t*)(w8 + 884736);  // 32 KB
    ushort_t* TEt   = (ushort_t*)(w8 + 917504);  // 8 KB
    ushort_t* msgsB = (ushort_t*)(w8 + 925696);  // 16 MB (bf16 msgs)
    float*    T1buf = (float*)(w8 + 17702912);   // 2 MB
    float*    T2buf = (float*)(w8 + 19800064);   // 2 MB
    float*    E3buf = (float*)(w8 + 21897216);   // 2 MB (ends ~24 MB)

    float* out_p  = (float*)d_out;            // [4,128,128]
    float* tri_p  = (float*)d_out + 65536;    // [4,128,128,128]

    prep_kernel<<<208, 256, 0, stream>>>(me_w, mlp1_w, mlp2_w, te1_w, te2_w, te3_w,
                                         Wme, Wm1, Wm2, TEt);
    node_kernel<<<512, 128, 0, stream>>>(node_fts, hidden, graph_fts,
                                         m1_w, m1_b, m2_w, m2_b, mg_w, mg_b,
                                         o1_w, o1_b, t1_w, t1_b, t2_w, t2_b,
                                         tg_w, tg_b, M1, M2, O1z, T1v, TT2);
    edge_kernel<<<512, 256, 0, stream>>>(edge_fts, Wme, me_b, Wm1, mlp1_b, Wm2, mlp2_b,
                                         TEt, te1_b, te2_b, te3_b,
                                         M1, M2, T1v, TT2, msgsB, T1buf, T2buf, E3buf);
    agg_out_kernel<<<512, 128, 0, stream>>>(msgsB, adj, O1z, o2_w, o2_b,
                                            norm_scale, norm_bias, out_p);
    tri_kernel<<<512, 256, 0, stream>>>(T1buf, T2buf, E3buf, o3_w, o3_b,
                                        norm_scale, norm_bias, tri_p);
}

// Round 3
// 132.348 us; speedup vs baseline: 1.8358x; 1.0997x over previous
//
#include <hip/hip_runtime.h>
#include <hip/hip_bf16.h>
#include <cstddef>
#include <cstdint>

typedef __attribute__((ext_vector_type(8))) short bf16x8;
typedef __attribute__((ext_vector_type(4))) float f32x4;
typedef unsigned short ushort_t;

__device__ __forceinline__ ushort_t f2b(float f) {
    uint32_t x = __float_as_uint(f);
    uint32_t r = (x + 0x7FFFu + ((x >> 16) & 1u)) >> 16;   // RNE
    return (ushort_t)r;
}
__device__ __forceinline__ float b2f(ushort_t u) {
    return __uint_as_float(((uint32_t)u) << 16);
}

// ---------------------------------------------------------------------------
// prep: build all bf16-transposed weights + folded graph biases.
//  Wnt[416][256]: cols of the node GEMM = m1|m2|o1|t1|t2|pad  (o-major)
//  Wme/Wm1/Wm2[128][128]: edge-chain weights transposed
//  TEt[32][128]: te1|te2|te3 padded, o-major
//  G1[4][128] = graph@mg_w + m1_b + mg_b ;  TG[4][8] = graph@tg_w + t2_b + tg_b
// ---------------------------------------------------------------------------
__global__ void prep_kernel(const float* __restrict__ m1_w, const float* __restrict__ m2_w,
                            const float* __restrict__ o1_w, const float* __restrict__ t1_w,
                            const float* __restrict__ t2_w,
                            const float* __restrict__ me_w, const float* __restrict__ mlp1_w,
                            const float* __restrict__ mlp2_w,
                            const float* __restrict__ te1_w, const float* __restrict__ te2_w,
                            const float* __restrict__ te3_w,
                            const float* __restrict__ graph_fts,
                            const float* __restrict__ mg_w, const float* __restrict__ mg_b,
                            const float* __restrict__ m1_b,
                            const float* __restrict__ tg_w, const float* __restrict__ t2_b,
                            const float* __restrict__ tg_b,
                            ushort_t* __restrict__ Wnt,
                            ushort_t* __restrict__ Wme, ushort_t* __restrict__ Wm1,
                            ushort_t* __restrict__ Wm2, ushort_t* __restrict__ TEt,
                            float* __restrict__ G1, float* __restrict__ TG) {
    int idx = blockIdx.x * 256 + threadIdx.x;
    if (idx < 106496) {                       // Wnt: o*256 + k
        int o = idx >> 8, k = idx & 255;
        float v = 0.0f;
        if (o < 128)       v = m1_w[k * 128 + o];
        else if (o < 256)  v = m2_w[k * 128 + (o - 128)];
        else if (o < 384)  v = o1_w[k * 128 + (o - 256)];
        else if (o < 392)  v = t1_w[k * 8 + (o - 384)];
        else if (o < 400)  v = t2_w[k * 8 + (o - 392)];
        Wnt[idx] = f2b(v);
    } else if (idx < 122880) {
        int t = idx - 106496, o = t >> 7, h = t & 127;
        Wme[t] = f2b(me_w[h * 128 + o]);
    } else if (idx < 139264) {
        int t = idx - 122880, o = t >> 7, h = t & 127;
        Wm1[t] = f2b(mlp1_w[h * 128 + o]);
    } else if (idx < 155648) {
        int t = idx - 139264, o = t >> 7, h = t & 127;
        Wm2[t] = f2b(mlp2_w[h * 128 + o]);
    } else if (idx < 159744) {
        int t = idx - 155648, c = t >> 7, h = t & 127;
        float v = 0.0f;
        if (c < 8)       v = te1_w[h * 8 + c];
        else if (c < 16) v = te2_w[h * 8 + (c - 8)];
        else if (c < 24) v = te3_w[h * 8 + (c - 16)];
        TEt[t] = f2b(v);
    } else if (idx < 160256) {                // G1
        int t = idx - 159744, b = t >> 7, h = t & 127;
        float a = m1_b[h] + mg_b[h];
        #pragma unroll 4
        for (int k = 0; k < 128; k++) a = fmaf(graph_fts[b * 128 + k], mg_w[k * 128 + h], a);
        G1[t] = a;
    } else if (idx < 160288) {                // TG
        int t = idx - 160256, b = t >> 3, tt = t & 7;
        float a = t2_b[tt] + tg_b[tt];
        #pragma unroll 4
        for (int k = 0; k < 128; k++) a = fmaf(graph_fts[b * 128 + k], tg_w[k * 8 + tt], a);
        TG[t] = a;
    }
}

// ---------------------------------------------------------------------------
// node GEMM (MFMA bf16): Z[512x256] @ Wnt^T -> {M1,M2,O1z,T1v,TT2}
// 16 blocks x 256 threads; block = 32 rows of Z staged bf16-swizzled in LDS.
// Wave w takes col-tiles mt = w, w+4, ... (26 tiles of 16 cols; tile 25 = pad)
// ---------------------------------------------------------------------------
__global__ __launch_bounds__(256)
void node_gemm(const float* __restrict__ node_fts, const float* __restrict__ hidden,
               const ushort_t* __restrict__ Wnt,
               const float* __restrict__ G1, const float* __restrict__ m2_b,
               const float* __restrict__ o1_b, const float* __restrict__ t1_b,
               const float* __restrict__ TG,
               float* __restrict__ M1, float* __restrict__ M2, float* __restrict__ O1z,
               float* __restrict__ T1v, float* __restrict__ TT2) {
    __shared__ ushort_t Zs[32 * 256];         // 16 KB, swizzled
    char* Zb = (char*)Zs;
    const int tid = threadIdx.x;
    const int blk = blockIdx.x;               // 16 blocks
    const int b = blk >> 2, q = blk & 3;
    const int row0 = b * 128 + q * 32;
    const int w = tid >> 6, l = tid & 63, g = l >> 4, lq = l & 15;

    // stage Z = [node | hidden] rows row0..row0+31, fp32 -> bf16 swizzled
    const float4* nsrc = reinterpret_cast<const float4*>(node_fts + (size_t)row0 * 128);
    const float4* hsrc = reinterpret_cast<const float4*>(hidden + (size_t)row0 * 128);
    #pragma unroll
    for (int p = 0; p < 8; p++) {
        int idx = tid + p * 256;              // float4 index 0..2047
        int r = idx >> 6, c4 = idx & 63;      // 64 float4 per 256-col row
        float4 v = (c4 < 32) ? nsrc[r * 32 + c4] : hsrc[r * 32 + (c4 - 32)];
        uint2 pk;
        pk.x = (uint32_t)f2b(v.x) | ((uint32_t)f2b(v.y) << 16);
        pk.y = (uint32_t)f2b(v.z) | ((uint32_t)f2b(v.w) << 16);
        *reinterpret_cast<uint2*>(Zb + r * 512 + (((c4 >> 1) ^ (r & 7)) << 4) + (c4 & 1) * 8) = pk;
    }
    __syncthreads();

    for (int mt = w; mt < 26; mt += 4) {
        f32x4 acc0 = (f32x4){0.f, 0.f, 0.f, 0.f};
        f32x4 acc1 = (f32x4){0.f, 0.f, 0.f, 0.f};
        const ushort_t* arow = Wnt + (size_t)(mt * 16 + lq) * 256;
        #pragma unroll
        for (int ks = 0; ks < 8; ks++) {
            bf16x8 a = *reinterpret_cast<const bf16x8*>(arow + ks * 32 + g * 8);
            int j0 = lq, j1 = 16 + lq;
            bf16x8 b0 = *reinterpret_cast<const bf16x8*>(Zb + j0 * 512 + (((ks * 4 + g) ^ (j0 & 7)) << 4));
            bf16x8 b1 = *reinterpret_cast<const bf16x8*>(Zb + j1 * 512 + (((ks * 4 + g) ^ (j1 & 7)) << 4));
            acc0 = __builtin_amdgcn_mfma_f32_16x16x32_bf16(a, b0, acc0, 0, 0, 0);
            acc1 = __builtin_amdgcn_mfma_f32_16x16x32_bf16(a, b1, acc1, 0, 0, 0);
        }
        #pragma unroll
        for (int half = 0; half < 2; half++) {
            const f32x4 acc = half ? acc1 : acc0;
            const int grow = row0 + half * 16 + lq;
            #pragma unroll
            for (int c = 0; c < 4; c++) {
                int o = mt * 16 + g * 4 + c;
                float v = acc[c];
                if (o < 128)       M1[(size_t)grow * 128 + o] = v + G1[b * 128 + o];
                else if (o < 256)  M2[(size_t)grow * 128 + (o - 128)] = v + m2_b[o - 128];
                else if (o < 384)  O1z[(size_t)grow * 128 + (o - 256)] = v + o1_b[o - 256];
                else if (o < 392)  T1v[(size_t)grow * 8 + (o - 384)] = v + t1_b[o - 384];
                else if (o < 400)  TT2[(size_t)grow * 8 + (o - 392)] = v + TG[b * 8 + (o - 392)];
            }
        }
    }
}

// ---------------------------------------------------------------------------
// edge kernel, MFMA bf16 (unchanged from R1)
// ---------------------------------------------------------------------------
__device__ __forceinline__ void mm128(const ushort_t* __restrict__ Wt, const char* Xb,
                                      f32x4 acc[4][4], int o_blk, int j_blk, int g, int lq) {
    #pragma unroll
    for (int ks = 0; ks < 4; ks++) {
        bf16x8 a[4], bb[4];
        #pragma unroll
        for (int m = 0; m < 4; m++)
            a[m] = *reinterpret_cast<const bf16x8*>(Wt + (size_t)(o_blk + m * 16 + lq) * 128 + ks * 32 + g * 8);
        #pragma unroll
        for (int n = 0; n < 4; n++) {
            int j = j_blk + n * 16 + lq;
            bb[n] = *reinterpret_cast<const bf16x8*>(Xb + j * 256 + (((ks * 4 + g) ^ (j & 7)) << 4));
        }
        #pragma unroll
        for (int m = 0; m < 4; m++)
            #pragma unroll
            for (int n = 0; n < 4; n++)
                acc[m][n] = __builtin_amdgcn_mfma_f32_16x16x32_bf16(a[m], bb[n], acc[m][n], 0, 0, 0);
    }
}

__global__ __launch_bounds__(256, 2)
void edge_kernel(const float* __restrict__ edge_fts,
                 const ushort_t* __restrict__ Wme, const float* __restrict__ me_b,
                 const ushort_t* __restrict__ Wm1, const float* __restrict__ mlp1_b,
                 const ushort_t* __restrict__ Wm2, const float* __restrict__ mlp2_b,
                 const ushort_t* __restrict__ TEt,
                 const float* __restrict__ te1_b, const float* __restrict__ te2_b,
                 const float* __restrict__ te3_b,
                 const float* __restrict__ M1,  const float* __restrict__ M2,
                 const float* __restrict__ T1v, const float* __restrict__ TT2,
                 ushort_t* __restrict__ msgsB, float* __restrict__ T1buf,
                 float* __restrict__ T2buf, float* __restrict__ E3buf) {
    __shared__ ushort_t Xs[16384];     // 32 KB bf16 tile, swizzled
    char* Xb = (char*)Xs;
    const int tid = threadIdx.x;
    const int b  = blockIdx.x >> 7;
    const int ie = blockIdx.x & 127;
    const int w = tid >> 6, l = tid & 63, g = l >> 4, lq = l & 15;
    const int o_blk = (w & 1) * 64, j_blk = (w >> 1) * 64;

    // ---- stage 0: global fp32 -> bf16 swizzled LDS ----
    const float4* esrc = reinterpret_cast<const float4*>(edge_fts + (size_t)(b * 128 + ie) * 16384);
    #pragma unroll
    for (int p = 0; p < 16; p++) {
        int idx = tid + p * 256;       // float4 index 0..4095
        int r = idx >> 5, c4 = idx & 31;
        float4 v = esrc[idx];
        uint2 pk;
        pk.x = (uint32_t)f2b(v.x) | ((uint32_t)f2b(v.y) << 16);
        pk.y = (uint32_t)f2b(v.z) | ((uint32_t)f2b(v.w) << 16);
        *reinterpret_cast<uint2*>(Xb + r * 256 + (((c4 >> 1) ^ (r & 7)) << 4) + (c4 & 1) * 8) = pk;
    }
    __syncthreads();

    // ---- te projections ----
    {
        const int m_te = w & 1;
        const ushort_t* At = TEt + m_te * 16 * 128;
        f32x4 acc[4];
        #pragma unroll
        for (int n = 0; n < 4; n++) acc[n] = (f32x4){0.f, 0.f, 0.f, 0.f};
        #pragma unroll
        for (int ks = 0; ks < 4; ks++) {
            bf16x8 a = *reinterpret_cast<const bf16x8*>(At + lq * 128 + ks * 32 + g * 8);
            #pragma unroll
            for (int n = 0; n < 4; n++) {
                int j = j_blk + n * 16 + lq;
                bf16x8 bbv = *reinterpret_cast<const bf16x8*>(Xb + j * 256 + (((ks * 4 + g) ^ (j & 7)) << 4));
                acc[n] = __builtin_amdgcn_mfma_f32_16x16x32_bf16(a, bbv, acc[n], 0, 0, 0);
            }
        }
        if (m_te == 0) {
            if (g < 2) {   // te1: T1buf[b][j][ie][t]
                int t0 = g * 4;
                const float4 eb = *reinterpret_cast<const float4*>(te1_b + t0);
                const float4 tv = *reinterpret_cast<const float4*>(T1v + (size_t)(b * 128 + ie) * 8 + t0);
                #pragma unroll
                for (int n = 0; n < 4; n++) {
                    int j = j_blk + n * 16 + lq;
                    float4 o4 = make_float4(acc[n][0] + eb.x + tv.x, acc[n][1] + eb.y + tv.y,
                                            acc[n][2] + eb.z + tv.z, acc[n][3] + eb.w + tv.w);
                    *reinterpret_cast<float4*>(T1buf + ((size_t)(b * 128 + j) * 128 + ie) * 8 + t0) = o4;
                }
            } else {       // te2: T2buf[b][ie][j][t]
                int t0 = g * 4 - 8;
                const float4 eb = *reinterpret_cast<const float4*>(te2_b + t0);
                #pragma unroll
                for (int n = 0; n < 4; n++) {
                    int j = j_blk + n * 16 + lq;
                    float4 o4 = make_float4(acc[n][0] + eb.x, acc[n][1] + eb.y,
                                            acc[n][2] + eb.z, acc[n][3] + eb.w);
                    *reinterpret_cast<float4*>(T2buf + ((size_t)(b * 128 + ie) * 128 + j) * 8 + t0) = o4;
                }
            }
        } else if (g < 2) { // te3: E3buf[b][ie][j][t] + TT2[b,ie] + T1v[b,j]
            int t0 = g * 4;
            const float4 eb = *reinterpret_cast<const float4*>(te3_b + t0);
            const float4 t2v = *reinterpret_cast<const float4*>(TT2 + (size_t)(b * 128 + ie) * 8 + t0);
            #pragma unroll
            for (int n = 0; n < 4; n++) {
                int j = j_blk + n * 16 + lq;
                const float4 t3v = *reinterpret_cast<const float4*>(T1v + (size_t)(b * 128 + j) * 8 + t0);
                float4 o4 = make_float4(acc[n][0] + eb.x + t2v.x + t3v.x,
                                        acc[n][1] + eb.y + t2v.y + t3v.y,
                                        acc[n][2] + eb.z + t2v.z + t3v.z,
                                        acc[n][3] + eb.w + t2v.w + t3v.w);
                *reinterpret_cast<float4*>(E3buf + ((size_t)(b * 128 + ie) * 128 + j) * 8 + t0) = o4;
            }
        }
    }

    f32x4 acc[4][4];

    // ================= stage 1: X = relu(X@me_w + me_b + M1[b,j] + M2[b,ie]) =================
    #pragma unroll
    for (int m = 0; m < 4; m++)
        #pragma unroll
        for (int n = 0; n < 4; n++) acc[m][n] = (f32x4){0.f, 0.f, 0.f, 0.f};
    mm128(Wme, Xb, acc, o_blk, j_blk, g, lq);
    {
        float4 bc[4];
        #pragma unroll
        for (int m = 0; m < 4; m++) {
            int o0 = o_blk + m * 16 + g * 4;
            const float4 eb = *reinterpret_cast<const float4*>(me_b + o0);
            const float4 m2 = *reinterpret_cast<const float4*>(M2 + (size_t)(b * 128 + ie) * 128 + o0);
            bc[m] = make_float4(eb.x + m2.x, eb.y + m2.y, eb.z + m2.z, eb.w + m2.w);
        }
        __syncthreads();
        #pragma unroll
        for (int m = 0; m < 4; m++) {
            int o0 = o_blk + m * 16 + g * 4;
            #pragma unroll
            for (int n = 0; n < 4; n++) {
                int j = j_blk + n * 16 + lq;
                const float4 m1 = *reinterpret_cast<const float4*>(M1 + (size_t)(b * 128 + j) * 128 + o0);
                float r0 = fmaxf(acc[m][n][0] + bc[m].x + m1.x, 0.f);
                float r1 = fmaxf(acc[m][n][1] + bc[m].y + m1.y, 0.f);
                float r2 = fmaxf(acc[m][n][2] + bc[m].z + m1.z, 0.f);
                float r3 = fmaxf(acc[m][n][3] + bc[m].w + m1.w, 0.f);
                uint2 pk;
                pk.x = (uint32_t)f2b(r0) | ((uint32_t)f2b(r1) << 16);
                pk.y = (uint32_t)f2b(r2) | ((uint32_t)f2b(r3) << 16);
                *reinterpret_cast<uint2*>(Xb + j * 256 + ((((o0 >> 3) ^ (j & 7))) << 4) + (o0 & 7) * 2) = pk;
            }
        }
        __syncthreads();
    }

    // ================= stage 2: X = relu(X@mlp1_w + mlp1_b) =================
    #pragma unroll
    for (int m = 0; m < 4; m++)
        #pragma unroll
        for (int n = 0; n < 4; n++) acc[m][n] = (f32x4){0.f, 0.f, 0.f, 0.f};
    mm128(Wm1, Xb, acc, o_blk, j_blk, g, lq);
    {
        float4 bc[4];
        #pragma unroll
        for (int m = 0; m < 4; m++) {
            int o0 = o_blk + m * 16 + g * 4;
            bc[m] = *reinterpret_cast<const float4*>(mlp1_b + o0);
        }
        __syncthreads();
        #pragma unroll
        for (int m = 0; m < 4; m++) {
            int o0 = o_blk + m * 16 + g * 4;
            #pragma unroll
            for (int n = 0; n < 4; n++) {
                int j = j_blk + n * 16 + lq;
                float r0 = fmaxf(acc[m][n][0] + bc[m].x, 0.f);
                float r1 = fmaxf(acc[m][n][1] + bc[m].y, 0.f);
                float r2 = fmaxf(acc[m][n][2] + bc[m].z, 0.f);
                float r3 = fmaxf(acc[m][n][3] + bc[m].w, 0.f);
                uint2 pk;
                pk.x = (uint32_t)f2b(r0) | ((uint32_t)f2b(r1) << 16);
                pk.y = (uint32_t)f2b(r2) | ((uint32_t)f2b(r3) << 16);
                *reinterpret_cast<uint2*>(Xb + j * 256 + ((((o0 >> 3) ^ (j & 7))) << 4) + (o0 & 7) * 2) = pk;
            }
        }
        __syncthreads();
    }

    // ================= stage 3: msgs = X@mlp2_w + mlp2_b =================
    #pragma unroll
    for (int m = 0; m < 4; m++)
        #pragma unroll
        for (int n = 0; n < 4; n++) acc[m][n] = (f32x4){0.f, 0.f, 0.f, 0.f};
    mm128(Wm2, Xb, acc, o_blk, j_blk, g, lq);
    {
        float4 bc[4];
        #pragma unroll
        for (int m = 0; m < 4; m++) {
            int o0 = o_blk + m * 16 + g * 4;
            bc[m] = *reinterpret_cast<const float4*>(mlp2_b + o0);
        }
        __syncthreads();
        #pragma unroll
        for (int m = 0; m < 4; m++) {
            int o0 = o_blk + m * 16 + g * 4;
            #pragma unroll
            for (int n = 0; n < 4; n++) {
                int j = j_blk + n * 16 + lq;
                float r0 = acc[m][n][0] + bc[m].x;
                float r1 = acc[m][n][1] + bc[m].y;
                float r2 = acc[m][n][2] + bc[m].z;
                float r3 = acc[m][n][3] + bc[m].w;
                uint2 pk;
                pk.x = (uint32_t)f2b(r0) | ((uint32_t)f2b(r1) << 16);
                pk.y = (uint32_t)f2b(r2) | ((uint32_t)f2b(r3) << 16);
                *reinterpret_cast<uint2*>(Xb + j * 256 + ((((o0 >> 3) ^ (j & 7))) << 4) + (o0 & 7) * 2) = pk;
            }
        }
        __syncthreads();
    }

    // ---- coalesced de-swizzle copy-out: msgsB[b][ie][j][h] bf16 ----
    {
        ushort_t* mdst = msgsB + (size_t)(b * 128 + ie) * 16384;
        const int r0 = tid >> 4, sc = tid & 15;
        #pragma unroll
        for (int q = 0; q < 8; q++) {
            int r = r0 + q * 16;
            uint4 v = *reinterpret_cast<const uint4*>(Xb + r * 256 + sc * 16);
            int logical = sc ^ (r & 7);
            *reinterpret_cast<uint4*>(mdst + r * 128 + logical * 8) = v;
        }
    }
}

// ---------------------------------------------------------------------------
// masked max aggregation over i + output head (msgs bf16)
// ---------------------------------------------------------------------------
__global__ __launch_bounds__(128)
void agg_out_kernel(const ushort_t* __restrict__ msgsB, const int* __restrict__ adj,
                    const float* __restrict__ O1z,
                    const float* __restrict__ o2_w, const float* __restrict__ o2_b,
                    const float* __restrict__ scale, const float* __restrict__ bias,
                    float* __restrict__ out) {
    __shared__ float aggs[128];
    __shared__ float red[2][2];
    const int b = blockIdx.x >> 7, j = blockIdx.x & 127;
    const int h = threadIdx.x;
    const ushort_t* mbase = msgsB + (size_t)b * 2097152 + (size_t)j * 128 + h;
    const int* abase = adj + b * 16384 + j;
    float acc = -1e9f;
    #pragma unroll 4
    for (int i = 0; i < 128; i++) {
        float m = b2f(mbase[(size_t)i * 16384]);
        int a = abase[i * 128];
        acc = fmaxf(acc, (a == 1) ? m : -1e9f);
    }
    aggs[h] = acc;
    __syncthreads();
    float val = o2_b[h] + O1z[(size_t)(b * 128 + j) * 128 + h];
    #pragma unroll 4
    for (int k = 0; k < 128; k++) val = fmaf(aggs[k], o2_w[k * 128 + h], val);
    float v = fmaxf(val, 0.0f);
    float s = v, s2 = v * v;
    #pragma unroll
    for (int off = 32; off >= 1; off >>= 1) {
        s += __shfl_down(s, off, 64);
        s2 += __shfl_down(s2, off, 64);
    }
    const int w = h >> 6;
    if ((h & 63) == 0) { red[w][0] = s; red[w][1] = s2; }
    __syncthreads();
    const float tot = red[0][0] + red[1][0];
    const float tot2 = red[0][1] + red[1][1];
    const float mean = tot * (1.0f / 128.0f);
    const float var = tot2 * (1.0f / 128.0f) - mean * mean;
    const float rstd = rsqrtf(var + 1e-5f);
    out[(size_t)(b * 128 + j) * 128 + h] = (v - mean) * rstd * scale[h] + bias[h];
}

// ---------------------------------------------------------------------------
// triplet kernel: phase1 = max over i; phase2 = wave-per-row
// ---------------------------------------------------------------------------
__global__ __launch_bounds__(256)
void tri_kernel(const float* __restrict__ T1buf, const float* __restrict__ T2buf,
                const float* __restrict__ E3buf, const float* __restrict__ o3_w,
                const float* __restrict__ o3_b, const float* __restrict__ scale,
                const float* __restrict__ bias, float* __restrict__ tri_out) {
    __shared__ __align__(16) float T1s[1024];
    __shared__ __align__(16) float E3s[1024];
    __shared__ __align__(16) float o3s[1024];
    __shared__ __align__(16) float Ps[2][128][8];
    const int b = blockIdx.x >> 7, jf = blockIdx.x & 127;
    const int tid = threadIdx.x;
    {
        reinterpret_cast<float4*>(T1s)[tid] =
            reinterpret_cast<const float4*>(T1buf + (size_t)(b * 128 + jf) * 1024)[tid];
        reinterpret_cast<float4*>(E3s)[tid] =
            reinterpret_cast<const float4*>(E3buf + (size_t)(b * 128 + jf) * 1024)[tid];
        reinterpret_cast<float4*>(o3s)[tid] = reinterpret_cast<const float4*>(o3_w)[tid];
    }
    __syncthreads();

    {
        const int kf = tid & 127, ih = tid >> 7;
        float a8[8];
        #pragma unroll
        for (int t = 0; t < 8; t++) a8[t] = -3.0e38f;
        const float4* t2p = reinterpret_cast<const float4*>(T2buf + (size_t)b * 131072);
        #pragma unroll 2
        for (int ii = 0; ii < 64; ++ii) {
            const int i = ih * 64 + ii;
            const float4 p = t2p[(i * 128 + kf) * 2];
            const float4 q = t2p[(i * 128 + kf) * 2 + 1];
            const float* t1r = &T1s[i * 8];
            a8[0] = fmaxf(a8[0], t1r[0] + p.x);
            a8[1] = fmaxf(a8[1], t1r[1] + p.y);
            a8[2] = fmaxf(a8[2], t1r[2] + p.z);
            a8[3] = fmaxf(a8[3], t1r[3] + p.w);
            a8[4] = fmaxf(a8[4], t1r[4] + q.x);
            a8[5] = fmaxf(a8[5], t1r[5] + q.y);
            a8[6] = fmaxf(a8[6], t1r[6] + q.z);
            a8[7] = fmaxf(a8[7], t1r[7] + q.w);
        }
        #pragma unroll
        for (int t = 0; t < 8; t++) Ps[ih][kf][t] = a8[t];
    }
    __syncthreads();

    const int w = tid >> 6, l = tid & 63;
    const float ob0 = o3_b[l],     ob1 = o3_b[l + 64];
    const float sc0 = scale[l],    sc1 = scale[l + 64];
    const float bi0 = bias[l],     bi1 = bias[l + 64];
    for (int kk = 0; kk < 32; ++kk) {
        const int kf = w * 32 + kk;
        float m8[8];
        #pragma unroll
        for (int t = 0; t < 8; t++)
            m8[t] = fmaxf(Ps[0][kf][t], Ps[1][kf][t]) + E3s[kf * 8 + t];
        float v0 = ob0, v1 = ob1;
        #pragma unroll
        for (int t = 0; t < 8; t++) {
            v0 = fmaf(m8[t], o3s[t * 128 + l], v0);
            v1 = fmaf(m8[t], o3s[t * 128 + l + 64], v1);
        }
        v0 = fmaxf(v0, 0.0f);
        v1 = fmaxf(v1, 0.0f);
        float s = v0 + v1, s2 = v0 * v0 + v1 * v1;
        #pragma unroll
        for (int off = 32; off >= 1; off >>= 1) {
            s  += __shfl_xor(s, off, 64);
            s2 += __shfl_xor(s2, off, 64);
        }
        const float mean = s * (1.0f / 128.0f);
        const float var = s2 * (1.0f / 128.0f) - mean * mean;
        const float rstd = rsqrtf(var + 1e-5f);
        float* dst = tri_out + (size_t)((b * 128 + jf) * 128 + kf) * 128;
        dst[l]      = (v0 - mean) * rstd * sc0 + bi0;
        dst[l + 64] = (v1 - mean) * rstd * sc1 + bi1;
    }
}

// ---------------------------------------------------------------------------
extern "C" void kernel_launch(void* const* d_in, const int* in_sizes, int n_in,
                              void* d_out, int out_size, void* d_ws, size_t ws_size,
                              hipStream_t stream) {
    const float* node_fts  = (const float*)d_in[0];
    const float* edge_fts  = (const float*)d_in[1];
    const float* graph_fts = (const float*)d_in[2];
    const float* hidden    = (const float*)d_in[3];
    const int*   adj       = (const int*)d_in[4];
    const float* m1_w = (const float*)d_in[5],  *m1_b = (const float*)d_in[6];
    const float* m2_w = (const float*)d_in[7],  *m2_b = (const float*)d_in[8];
    const float* me_w = (const float*)d_in[9],  *me_b = (const float*)d_in[10];
    const float* mg_w = (const float*)d_in[11], *mg_b = (const float*)d_in[12];
    const float* mlp1_w = (const float*)d_in[13], *mlp1_b = (const float*)d_in[14];
    const float* mlp2_w = (const float*)d_in[15], *mlp2_b = (const float*)d_in[16];
    const float* o1_w = (const float*)d_in[17], *o1_b = (const float*)d_in[18];
    const float* o2_w = (const float*)d_in[19], *o2_b = (const float*)d_in[20];
    const float* t1_w = (const float*)d_in[21], *t1_b = (const float*)d_in[22];
    const float* t2_w = (const float*)d_in[23], *t2_b = (const float*)d_in[24];
    const float* te1_w = (const float*)d_in[25], *te1_b = (const float*)d_in[26];
    const float* te2_w = (const float*)d_in[27], *te2_b = (const float*)d_in[28];
    const float* te3_w = (const float*)d_in[29], *te3_b = (const float*)d_in[30];
    const float* tg_w = (const float*)d_in[31], *tg_b = (const float*)d_in[32];
    const float* o3_w = (const float*)d_in[33], *o3_b = (const float*)d_in[34];
    const float* norm_scale = (const float*)d_in[35];
    const float* norm_bias  = (const float*)d_in[36];

    char* w8 = (char*)d_ws;
    float*    M1    = (float*)(w8 + 0);          // 256 KB
    float*    M2    = (float*)(w8 + 262144);     // 256 KB
    float*    O1z   = (float*)(w8 + 524288);     // 256 KB
    float*    T1v   = (float*)(w8 + 786432);     // 16 KB
    float*    TT2   = (float*)(w8 + 802816);     // 16 KB
    ushort_t* Wme   = (ushort_t*)(w8 + 819200);  // 32 KB
    ushort_t* Wm1   = (ushort_t*)(w8 + 851968);  // 32 KB
    ushort_t* Wm2   = (ushort_t*)(w8 + 884736);  // 32 KB
    ushort_t* TEt   = (ushort_t*)(w8 + 917504);  // 8 KB
    ushort_t* msgsB = (ushort_t*)(w8 + 925696);  // 16 MB
    float*    T1buf = (float*)(w8 + 17702912);   // 2 MB
    float*    T2buf = (float*)(w8 + 19800064);   // 2 MB
    float*    E3buf = (float*)(w8 + 21897216);   // 2 MB
    ushort_t* Wnt   = (ushort_t*)(w8 + 23994368);// 208 KB
    float*    G1    = (float*)(w8 + 24207360);   // 2 KB
    float*    TG    = (float*)(w8 + 24209408);   // 128 B

    float* out_p  = (float*)d_out;            // [4,128,128]
    float* tri_p  = (float*)d_out + 65536;    // [4,128,128,128]

    prep_kernel<<<627, 256, 0, stream>>>(m1_w, m2_w, o1_w, t1_w, t2_w,
                                         me_w, mlp1_w, mlp2_w, te1_w, te2_w, te3_w,
                                         graph_fts, mg_w, mg_b, m1_b, tg_w, t2_b, tg_b,
                                         Wnt, Wme, Wm1, Wm2, TEt, G1, TG);
    node_gemm<<<16, 256, 0, stream>>>(node_fts, hidden, Wnt, G1, m2_b, o1_b, t1_b, TG,
                                      M1, M2, O1z, T1v, TT2);
    edge_kernel<<<512, 256, 0, stream>>>(edge_fts, Wme, me_b, Wm1, mlp1_b, Wm2, mlp2_b,
                                         TEt, te1_b, te2_b, te3_b,
                                         M1, M2, T1v, TT2, msgsB, T1buf, T2buf, E3buf);
    agg_out_kernel<<<512, 128, 0, stream>>>(msgsB, adj, O1z, o2_w, o2_b,
                                            norm_scale, norm_bias, out_p);
    tri_kernel<<<512, 256, 0, stream>>>(T1buf, T2buf, E3buf, o3_w, o3_b,
                                        norm_scale, norm_bias, tri_p);
}

// Round 4
// 128.249 us; speedup vs baseline: 1.8945x; 1.0320x over previous
//
#include <hip/hip_runtime.h>
#include <hip/hip_bf16.h>
#include <cstddef>
#include <cstdint>

typedef __attribute__((ext_vector_type(8))) short bf16x8;
typedef __attribute__((ext_vector_type(4))) float f32x4;
typedef unsigned short ushort_t;

__device__ __forceinline__ ushort_t f2b(float f) {
    uint32_t x = __float_as_uint(f);
    uint32_t r = (x + 0x7FFFu + ((x >> 16) & 1u)) >> 16;   // RNE
    return (ushort_t)r;
}
__device__ __forceinline__ float b2f(ushort_t u) {
    return __uint_as_float(((uint32_t)u) << 16);
}

// ---------------------------------------------------------------------------
// prep: build all bf16-transposed weights + folded graph biases.
// ---------------------------------------------------------------------------
__global__ void prep_kernel(const float* __restrict__ m1_w, const float* __restrict__ m2_w,
                            const float* __restrict__ o1_w, const float* __restrict__ t1_w,
                            const float* __restrict__ t2_w,
                            const float* __restrict__ me_w, const float* __restrict__ mlp1_w,
                            const float* __restrict__ mlp2_w,
                            const float* __restrict__ te1_w, const float* __restrict__ te2_w,
                            const float* __restrict__ te3_w,
                            const float* __restrict__ graph_fts,
                            const float* __restrict__ mg_w, const float* __restrict__ mg_b,
                            const float* __restrict__ m1_b,
                            const float* __restrict__ tg_w, const float* __restrict__ t2_b,
                            const float* __restrict__ tg_b,
                            ushort_t* __restrict__ Wnt,
                            ushort_t* __restrict__ Wme, ushort_t* __restrict__ Wm1,
                            ushort_t* __restrict__ Wm2, ushort_t* __restrict__ TEt,
                            float* __restrict__ G1, float* __restrict__ TG) {
    int idx = blockIdx.x * 256 + threadIdx.x;
    if (idx < 106496) {                       // Wnt: o*256 + k
        int o = idx >> 8, k = idx & 255;
        float v = 0.0f;
        if (o < 128)       v = m1_w[k * 128 + o];
        else if (o < 256)  v = m2_w[k * 128 + (o - 128)];
        else if (o < 384)  v = o1_w[k * 128 + (o - 256)];
        else if (o < 392)  v = t1_w[k * 8 + (o - 384)];
        else if (o < 400)  v = t2_w[k * 8 + (o - 392)];
        Wnt[idx] = f2b(v);
    } else if (idx < 122880) {
        int t = idx - 106496, o = t >> 7, h = t & 127;
        Wme[t] = f2b(me_w[h * 128 + o]);
    } else if (idx < 139264) {
        int t = idx - 122880, o = t >> 7, h = t & 127;
        Wm1[t] = f2b(mlp1_w[h * 128 + o]);
    } else if (idx < 155648) {
        int t = idx - 139264, o = t >> 7, h = t & 127;
        Wm2[t] = f2b(mlp2_w[h * 128 + o]);
    } else if (idx < 159744) {
        int t = idx - 155648, c = t >> 7, h = t & 127;
        float v = 0.0f;
        if (c < 8)       v = te1_w[h * 8 + c];
        else if (c < 16) v = te2_w[h * 8 + (c - 8)];
        else if (c < 24) v = te3_w[h * 8 + (c - 16)];
        TEt[t] = f2b(v);
    } else if (idx < 160256) {                // G1
        int t = idx - 159744, b = t >> 7, h = t & 127;
        float a = m1_b[h] + mg_b[h];
        #pragma unroll 4
        for (int k = 0; k < 128; k++) a = fmaf(graph_fts[b * 128 + k], mg_w[k * 128 + h], a);
        G1[t] = a;
    } else if (idx < 160288) {                // TG
        int t = idx - 160256, b = t >> 3, tt = t & 7;
        float a = t2_b[tt] + tg_b[tt];
        #pragma unroll 4
        for (int k = 0; k < 128; k++) a = fmaf(graph_fts[b * 128 + k], tg_w[k * 8 + tt], a);
        TG[t] = a;
    }
}

// ---------------------------------------------------------------------------
// node GEMM (MFMA bf16): Z[512x256] @ Wnt^T -> {M1,M2,O1z,T1v,TT2}
// ---------------------------------------------------------------------------
__global__ __launch_bounds__(256)
void node_gemm(const float* __restrict__ node_fts, const float* __restrict__ hidden,
               const ushort_t* __restrict__ Wnt,
               const float* __restrict__ G1, const float* __restrict__ m2_b,
               const float* __restrict__ o1_b, const float* __restrict__ t1_b,
               const float* __restrict__ TG,
               float* __restrict__ M1, float* __restrict__ M2, float* __restrict__ O1z,
               float* __restrict__ T1v, float* __restrict__ TT2) {
    __shared__ ushort_t Zs[32 * 256];         // 16 KB, swizzled
    char* Zb = (char*)Zs;
    const int tid = threadIdx.x;
    const int blk = blockIdx.x;               // 16 blocks
    const int b = blk >> 2, q = blk & 3;
    const int row0 = b * 128 + q * 32;
    const int w = tid >> 6, l = tid & 63, g = l >> 4, lq = l & 15;

    const float4* nsrc = reinterpret_cast<const float4*>(node_fts + (size_t)row0 * 128);
    const float4* hsrc = reinterpret_cast<const float4*>(hidden + (size_t)row0 * 128);
    #pragma unroll
    for (int p = 0; p < 8; p++) {
        int idx = tid + p * 256;
        int r = idx >> 6, c4 = idx & 63;
        float4 v = (c4 < 32) ? nsrc[r * 32 + c4] : hsrc[r * 32 + (c4 - 32)];
        uint2 pk;
        pk.x = (uint32_t)f2b(v.x) | ((uint32_t)f2b(v.y) << 16);
        pk.y = (uint32_t)f2b(v.z) | ((uint32_t)f2b(v.w) << 16);
        *reinterpret_cast<uint2*>(Zb + r * 512 + (((c4 >> 1) ^ (r & 7)) << 4) + (c4 & 1) * 8) = pk;
    }
    __syncthreads();

    for (int mt = w; mt < 26; mt += 4) {
        f32x4 acc0 = (f32x4){0.f, 0.f, 0.f, 0.f};
        f32x4 acc1 = (f32x4){0.f, 0.f, 0.f, 0.f};
        const ushort_t* arow = Wnt + (size_t)(mt * 16 + lq) * 256;
        #pragma unroll
        for (int ks = 0; ks < 8; ks++) {
            bf16x8 a = *reinterpret_cast<const bf16x8*>(arow + ks * 32 + g * 8);
            int j0 = lq, j1 = 16 + lq;
            bf16x8 b0 = *reinterpret_cast<const bf16x8*>(Zb + j0 * 512 + (((ks * 4 + g) ^ (j0 & 7)) << 4));
            bf16x8 b1 = *reinterpret_cast<const bf16x8*>(Zb + j1 * 512 + (((ks * 4 + g) ^ (j1 & 7)) << 4));
            acc0 = __builtin_amdgcn_mfma_f32_16x16x32_bf16(a, b0, acc0, 0, 0, 0);
            acc1 = __builtin_amdgcn_mfma_f32_16x16x32_bf16(a, b1, acc1, 0, 0, 0);
        }
        #pragma unroll
        for (int half = 0; half < 2; half++) {
            const f32x4 acc = half ? acc1 : acc0;
            const int grow = row0 + half * 16 + lq;
            #pragma unroll
            for (int c = 0; c < 4; c++) {
                int o = mt * 16 + g * 4 + c;
                float v = acc[c];
                if (o < 128)       M1[(size_t)grow * 128 + o] = v + G1[b * 128 + o];
                else if (o < 256)  M2[(size_t)grow * 128 + (o - 128)] = v + m2_b[o - 128];
                else if (o < 384)  O1z[(size_t)grow * 128 + (o - 256)] = v + o1_b[o - 256];
                else if (o < 392)  T1v[(size_t)grow * 8 + (o - 384)] = v + t1_b[o - 384];
                else if (o < 400)  TT2[(size_t)grow * 8 + (o - 392)] = v + TG[b * 8 + (o - 392)];
            }
        }
    }
}

// ---------------------------------------------------------------------------
// edge kernel, MFMA bf16. Copy-out now writes msgsM[b][j][i][h] so the
// aggregation kernel streams contiguous slabs.
// ---------------------------------------------------------------------------
__device__ __forceinline__ void mm128(const ushort_t* __restrict__ Wt, const char* Xb,
                                      f32x4 acc[4][4], int o_blk, int j_blk, int g, int lq) {
    #pragma unroll
    for (int ks = 0; ks < 4; ks++) {
        bf16x8 a[4], bb[4];
        #pragma unroll
        for (int m = 0; m < 4; m++)
            a[m] = *reinterpret_cast<const bf16x8*>(Wt + (size_t)(o_blk + m * 16 + lq) * 128 + ks * 32 + g * 8);
        #pragma unroll
        for (int n = 0; n < 4; n++) {
            int j = j_blk + n * 16 + lq;
            bb[n] = *reinterpret_cast<const bf16x8*>(Xb + j * 256 + (((ks * 4 + g) ^ (j & 7)) << 4));
        }
        #pragma unroll
        for (int m = 0; m < 4; m++)
            #pragma unroll
            for (int n = 0; n < 4; n++)
                acc[m][n] = __builtin_amdgcn_mfma_f32_16x16x32_bf16(a[m], bb[n], acc[m][n], 0, 0, 0);
    }
}

__global__ __launch_bounds__(256, 2)
void edge_kernel(const float* __restrict__ edge_fts,
                 const ushort_t* __restrict__ Wme, const float* __restrict__ me_b,
                 const ushort_t* __restrict__ Wm1, const float* __restrict__ mlp1_b,
                 const ushort_t* __restrict__ Wm2, const float* __restrict__ mlp2_b,
                 const ushort_t* __restrict__ TEt,
                 const float* __restrict__ te1_b, const float* __restrict__ te2_b,
                 const float* __restrict__ te3_b,
                 const float* __restrict__ M1,  const float* __restrict__ M2,
                 const float* __restrict__ T1v, const float* __restrict__ TT2,
                 ushort_t* __restrict__ msgsM, float* __restrict__ T1buf,
                 float* __restrict__ T2buf, float* __restrict__ E3buf) {
    __shared__ ushort_t Xs[16384];     // 32 KB bf16 tile, swizzled
    char* Xb = (char*)Xs;
    const int tid = threadIdx.x;
    const int b  = blockIdx.x >> 7;
    const int ie = blockIdx.x & 127;
    const int w = tid >> 6, l = tid & 63, g = l >> 4, lq = l & 15;
    const int o_blk = (w & 1) * 64, j_blk = (w >> 1) * 64;

    // ---- stage 0: global fp32 -> bf16 swizzled LDS ----
    const float4* esrc = reinterpret_cast<const float4*>(edge_fts + (size_t)(b * 128 + ie) * 16384);
    #pragma unroll
    for (int p = 0; p < 16; p++) {
        int idx = tid + p * 256;
        int r = idx >> 5, c4 = idx & 31;
        float4 v = esrc[idx];
        uint2 pk;
        pk.x = (uint32_t)f2b(v.x) | ((uint32_t)f2b(v.y) << 16);
        pk.y = (uint32_t)f2b(v.z) | ((uint32_t)f2b(v.w) << 16);
        *reinterpret_cast<uint2*>(Xb + r * 256 + (((c4 >> 1) ^ (r & 7)) << 4) + (c4 & 1) * 8) = pk;
    }
    __syncthreads();

    // ---- te projections ----
    {
        const int m_te = w & 1;
        const ushort_t* At = TEt + m_te * 16 * 128;
        f32x4 acc[4];
        #pragma unroll
        for (int n = 0; n < 4; n++) acc[n] = (f32x4){0.f, 0.f, 0.f, 0.f};
        #pragma unroll
        for (int ks = 0; ks < 4; ks++) {
            bf16x8 a = *reinterpret_cast<const bf16x8*>(At + lq * 128 + ks * 32 + g * 8);
            #pragma unroll
            for (int n = 0; n < 4; n++) {
                int j = j_blk + n * 16 + lq;
                bf16x8 bbv = *reinterpret_cast<const bf16x8*>(Xb + j * 256 + (((ks * 4 + g) ^ (j & 7)) << 4));
                acc[n] = __builtin_amdgcn_mfma_f32_16x16x32_bf16(a, bbv, acc[n], 0, 0, 0);
            }
        }
        if (m_te == 0) {
            if (g < 2) {   // te1: T1buf[b][j][ie][t]
                int t0 = g * 4;
                const float4 eb = *reinterpret_cast<const float4*>(te1_b + t0);
                const float4 tv = *reinterpret_cast<const float4*>(T1v + (size_t)(b * 128 + ie) * 8 + t0);
                #pragma unroll
                for (int n = 0; n < 4; n++) {
                    int j = j_blk + n * 16 + lq;
                    float4 o4 = make_float4(acc[n][0] + eb.x + tv.x, acc[n][1] + eb.y + tv.y,
                                            acc[n][2] + eb.z + tv.z, acc[n][3] + eb.w + tv.w);
                    *reinterpret_cast<float4*>(T1buf + ((size_t)(b * 128 + j) * 128 + ie) * 8 + t0) = o4;
                }
            } else {       // te2: T2buf[b][ie][j][t]
                int t0 = g * 4 - 8;
                const float4 eb = *reinterpret_cast<const float4*>(te2_b + t0);
                #pragma unroll
                for (int n = 0; n < 4; n++) {
                    int j = j_blk + n * 16 + lq;
                    float4 o4 = make_float4(acc[n][0] + eb.x, acc[n][1] + eb.y,
                                            acc[n][2] + eb.z, acc[n][3] + eb.w);
                    *reinterpret_cast<float4*>(T2buf + ((size_t)(b * 128 + ie) * 128 + j) * 8 + t0) = o4;
                }
            }
        } else if (g < 2) { // te3: E3buf[b][ie][j][t] + TT2[b,ie] + T1v[b,j]
            int t0 = g * 4;
            const float4 eb = *reinterpret_cast<const float4*>(te3_b + t0);
            const float4 t2v = *reinterpret_cast<const float4*>(TT2 + (size_t)(b * 128 + ie) * 8 + t0);
            #pragma unroll
            for (int n = 0; n < 4; n++) {
                int j = j_blk + n * 16 + lq;
                const float4 t3v = *reinterpret_cast<const float4*>(T1v + (size_t)(b * 128 + j) * 8 + t0);
                float4 o4 = make_float4(acc[n][0] + eb.x + t2v.x + t3v.x,
                                        acc[n][1] + eb.y + t2v.y + t3v.y,
                                        acc[n][2] + eb.z + t2v.z + t3v.z,
                                        acc[n][3] + eb.w + t2v.w + t3v.w);
                *reinterpret_cast<float4*>(E3buf + ((size_t)(b * 128 + ie) * 128 + j) * 8 + t0) = o4;
            }
        }
    }

    f32x4 acc[4][4];

    // ================= stage 1 =================
    #pragma unroll
    for (int m = 0; m < 4; m++)
        #pragma unroll
        for (int n = 0; n < 4; n++) acc[m][n] = (f32x4){0.f, 0.f, 0.f, 0.f};
    mm128(Wme, Xb, acc, o_blk, j_blk, g, lq);
    {
        float4 bc[4];
        #pragma unroll
        for (int m = 0; m < 4; m++) {
            int o0 = o_blk + m * 16 + g * 4;
            const float4 eb = *reinterpret_cast<const float4*>(me_b + o0);
            const float4 m2 = *reinterpret_cast<const float4*>(M2 + (size_t)(b * 128 + ie) * 128 + o0);
            bc[m] = make_float4(eb.x + m2.x, eb.y + m2.y, eb.z + m2.z, eb.w + m2.w);
        }
        __syncthreads();
        #pragma unroll
        for (int m = 0; m < 4; m++) {
            int o0 = o_blk + m * 16 + g * 4;
            #pragma unroll
            for (int n = 0; n < 4; n++) {
                int j = j_blk + n * 16 + lq;
                const float4 m1 = *reinterpret_cast<const float4*>(M1 + (size_t)(b * 128 + j) * 128 + o0);
                float r0 = fmaxf(acc[m][n][0] + bc[m].x + m1.x, 0.f);
                float r1 = fmaxf(acc[m][n][1] + bc[m].y + m1.y, 0.f);
                float r2 = fmaxf(acc[m][n][2] + bc[m].z + m1.z, 0.f);
                float r3 = fmaxf(acc[m][n][3] + bc[m].w + m1.w, 0.f);
                uint2 pk;
                pk.x = (uint32_t)f2b(r0) | ((uint32_t)f2b(r1) << 16);
                pk.y = (uint32_t)f2b(r2) | ((uint32_t)f2b(r3) << 16);
                *reinterpret_cast<uint2*>(Xb + j * 256 + ((((o0 >> 3) ^ (j & 7))) << 4) + (o0 & 7) * 2) = pk;
            }
        }
        __syncthreads();
    }

    // ================= stage 2 =================
    #pragma unroll
    for (int m = 0; m < 4; m++)
        #pragma unroll
        for (int n = 0; n < 4; n++) acc[m][n] = (f32x4){0.f, 0.f, 0.f, 0.f};
    mm128(Wm1, Xb, acc, o_blk, j_blk, g, lq);
    {
        float4 bc[4];
        #pragma unroll
        for (int m = 0; m < 4; m++) {
            int o0 = o_blk + m * 16 + g * 4;
            bc[m] = *reinterpret_cast<const float4*>(mlp1_b + o0);
        }
        __syncthreads();
        #pragma unroll
        for (int m = 0; m < 4; m++) {
            int o0 = o_blk + m * 16 + g * 4;
            #pragma unroll
            for (int n = 0; n < 4; n++) {
                int j = j_blk + n * 16 + lq;
                float r0 = fmaxf(acc[m][n][0] + bc[m].x, 0.f);
                float r1 = fmaxf(acc[m][n][1] + bc[m].y, 0.f);
                float r2 = fmaxf(acc[m][n][2] + bc[m].z, 0.f);
                float r3 = fmaxf(acc[m][n][3] + bc[m].w, 0.f);
                uint2 pk;
                pk.x = (uint32_t)f2b(r0) | ((uint32_t)f2b(r1) << 16);
                pk.y = (uint32_t)f2b(r2) | ((uint32_t)f2b(r3) << 16);
                *reinterpret_cast<uint2*>(Xb + j * 256 + ((((o0 >> 3) ^ (j & 7))) << 4) + (o0 & 7) * 2) = pk;
            }
        }
        __syncthreads();
    }

    // ================= stage 3 =================
    #pragma unroll
    for (int m = 0; m < 4; m++)
        #pragma unroll
        for (int n = 0; n < 4; n++) acc[m][n] = (f32x4){0.f, 0.f, 0.f, 0.f};
    mm128(Wm2, Xb, acc, o_blk, j_blk, g, lq);
    {
        float4 bc[4];
        #pragma unroll
        for (int m = 0; m < 4; m++) {
            int o0 = o_blk + m * 16 + g * 4;
            bc[m] = *reinterpret_cast<const float4*>(mlp2_b + o0);
        }
        __syncthreads();
        #pragma unroll
        for (int m = 0; m < 4; m++) {
            int o0 = o_blk + m * 16 + g * 4;
            #pragma unroll
            for (int n = 0; n < 4; n++) {
                int j = j_blk + n * 16 + lq;
                float r0 = acc[m][n][0] + bc[m].x;
                float r1 = acc[m][n][1] + bc[m].y;
                float r2 = acc[m][n][2] + bc[m].z;
                float r3 = acc[m][n][3] + bc[m].w;
                uint2 pk;
                pk.x = (uint32_t)f2b(r0) | ((uint32_t)f2b(r1) << 16);
                pk.y = (uint32_t)f2b(r2) | ((uint32_t)f2b(r3) << 16);
                *reinterpret_cast<uint2*>(Xb + j * 256 + ((((o0 >> 3) ^ (j & 7))) << 4) + (o0 & 7) * 2) = pk;
            }
        }
        __syncthreads();
    }

    // ---- de-swizzle copy-out, transposed layout: msgsM[b][j=r][i=ie][h] ----
    {
        const int r0 = tid >> 4, sc = tid & 15;
        #pragma unroll
        for (int q = 0; q < 8; q++) {
            int r = r0 + q * 16;
            uint4 v = *reinterpret_cast<const uint4*>(Xb + r * 256 + sc * 16);
            int logical = sc ^ (r & 7);
            *reinterpret_cast<uint4*>(msgsM + ((size_t)(b * 128 + r) * 128 + ie) * 128 + logical * 8) = v;
        }
    }
}

// ---------------------------------------------------------------------------
// masked max aggregation (msgsM[b][j][i][h] bf16, contiguous per (b,j)) + head
// ---------------------------------------------------------------------------
__global__ __launch_bounds__(256)
void agg_out_kernel(const ushort_t* __restrict__ msgsM, const int* __restrict__ adj,
                    const float* __restrict__ O1z,
                    const float* __restrict__ o2_w, const float* __restrict__ o2_b,
                    const float* __restrict__ scale, const float* __restrict__ bias,
                    float* __restrict__ out) {
    __shared__ float aggs[4][128];
    __shared__ float fagg[128];
    __shared__ float red[2][2];
    const int b = blockIdx.x >> 7, j = blockIdx.x & 127;
    const int t = threadIdx.x;
    const int wv = t >> 6, ln = t & 63;
    const ushort_t* msrc = msgsM + (size_t)(b * 128 + j) * 16384;
    const int* arow = adj + b * 16384 + j;
    float a0 = -1e9f, a1 = -1e9f;
    #pragma unroll 8
    for (int s = 0; s < 32; s++) {
        const int i = s * 4 + wv;
        uint32_t u = *reinterpret_cast<const uint32_t*>(msrc + i * 128 + ln * 2);
        bool m = (arow[i * 128] == 1);
        float x0 = b2f((ushort_t)(u & 0xffffu));
        float x1 = b2f((ushort_t)(u >> 16));
        a0 = m ? fmaxf(a0, x0) : a0;
        a1 = m ? fmaxf(a1, x1) : a1;
    }
    aggs[wv][ln * 2]     = a0;
    aggs[wv][ln * 2 + 1] = a1;
    __syncthreads();
    if (t < 128)
        fagg[t] = fmaxf(fmaxf(aggs[0][t], aggs[1][t]), fmaxf(aggs[2][t], aggs[3][t]));
    __syncthreads();

    float v = 0.0f;
    if (t < 128) {
        float val = o2_b[t] + O1z[(size_t)(b * 128 + j) * 128 + t];
        #pragma unroll 4
        for (int k = 0; k < 128; k++) val = fmaf(fagg[k], o2_w[k * 128 + t], val);
        v = fmaxf(val, 0.0f);
    }
    float s = v, s2 = v * v;
    #pragma unroll
    for (int off = 32; off >= 1; off >>= 1) {
        s += __shfl_down(s, off, 64);
        s2 += __shfl_down(s2, off, 64);
    }
    if (t < 128 && (t & 63) == 0) { red[t >> 6][0] = s; red[t >> 6][1] = s2; }
    __syncthreads();
    if (t < 128) {
        const float tot = red[0][0] + red[1][0];
        const float tot2 = red[0][1] + red[1][1];
        const float mean = tot * (1.0f / 128.0f);
        const float var = tot2 * (1.0f / 128.0f) - mean * mean;
        const float rstd = rsqrtf(var + 1e-5f);
        out[(size_t)(b * 128 + j) * 128 + t] = (v - mean) * rstd * scale[t] + bias[t];
    }
}

// ---------------------------------------------------------------------------
// triplet kernel: 2 jf per block (T2 slab shared), phase2 wave-per-(jj,kf-half)
// ---------------------------------------------------------------------------
__global__ __launch_bounds__(256)
void tri_kernel(const float* __restrict__ T1buf, const float* __restrict__ T2buf,
                const float* __restrict__ E3buf, const float* __restrict__ o3_w,
                const float* __restrict__ o3_b, const float* __restrict__ scale,
                const float* __restrict__ bias, float* __restrict__ tri_out) {
    __shared__ __align__(16) float T1s[2][1024];
    __shared__ __align__(16) float E3s[2][1024];
    __shared__ __align__(16) float o3s[1024];
    __shared__ __align__(16) float Ps[2][2][128][8];
    const int b = blockIdx.x >> 6, jg = blockIdx.x & 63;
    const int jf0 = jg * 2;
    const int tid = threadIdx.x;
    {
        #pragma unroll
        for (int jj = 0; jj < 2; jj++) {
            reinterpret_cast<float4*>(T1s[jj])[tid] =
                reinterpret_cast<const float4*>(T1buf + (size_t)(b * 128 + jf0 + jj) * 1024)[tid];
            reinterpret_cast<float4*>(E3s[jj])[tid] =
                reinterpret_cast<const float4*>(E3buf + (size_t)(b * 128 + jf0 + jj) * 1024)[tid];
        }
        reinterpret_cast<float4*>(o3s)[tid] = reinterpret_cast<const float4*>(o3_w)[tid];
    }
    __syncthreads();

    {
        const int kf = tid & 127, ih = tid >> 7;
        float a8[2][8];
        #pragma unroll
        for (int jj = 0; jj < 2; jj++)
            #pragma unroll
            for (int t = 0; t < 8; t++) a8[jj][t] = -3.0e38f;
        const float4* t2p = reinterpret_cast<const float4*>(T2buf + (size_t)b * 131072);
        #pragma unroll 2
        for (int ii = 0; ii < 64; ++ii) {
            const int i = ih * 64 + ii;
            const float4 p = t2p[(i * 128 + kf) * 2];
            const float4 q = t2p[(i * 128 + kf) * 2 + 1];
            #pragma unroll
            for (int jj = 0; jj < 2; jj++) {
                const float* t1r = &T1s[jj][i * 8];
                a8[jj][0] = fmaxf(a8[jj][0], t1r[0] + p.x);
                a8[jj][1] = fmaxf(a8[jj][1], t1r[1] + p.y);
                a8[jj][2] = fmaxf(a8[jj][2], t1r[2] + p.z);
                a8[jj][3] = fmaxf(a8[jj][3], t1r[3] + p.w);
                a8[jj][4] = fmaxf(a8[jj][4], t1r[4] + q.x);
                a8[jj][5] = fmaxf(a8[jj][5], t1r[5] + q.y);
                a8[jj][6] = fmaxf(a8[jj][6], t1r[6] + q.z);
                a8[jj][7] = fmaxf(a8[jj][7], t1r[7] + q.w);
            }
        }
        #pragma unroll
        for (int jj = 0; jj < 2; jj++)
            #pragma unroll
            for (int t = 0; t < 8; t++) Ps[jj][ih][kf][t] = a8[jj][t];
    }
    __syncthreads();

    const int w = tid >> 6, l = tid & 63;
    const int jj = w >> 1, kf0 = (w & 1) * 64;
    const int jf = jf0 + jj;
    const float ob0 = o3_b[l],     ob1 = o3_b[l + 64];
    const float sc0 = scale[l],    sc1 = scale[l + 64];
    const float bi0 = bias[l],     bi1 = bias[l + 64];
    for (int kk = 0; kk < 64; ++kk) {
        const int kf = kf0 + kk;
        float m8[8];
        #pragma unroll
        for (int t = 0; t < 8; t++)
            m8[t] = fmaxf(Ps[jj][0][kf][t], Ps[jj][1][kf][t]) + E3s[jj][kf * 8 + t];
        float v0 = ob0, v1 = ob1;
        #pragma unroll
        for (int t = 0; t < 8; t++) {
            v0 = fmaf(m8[t], o3s[t * 128 + l], v0);
            v1 = fmaf(m8[t], o3s[t * 128 + l + 64], v1);
        }
        v0 = fmaxf(v0, 0.0f);
        v1 = fmaxf(v1, 0.0f);
        float s = v0 + v1, s2 = v0 * v0 + v1 * v1;
        #pragma unroll
        for (int off = 32; off >= 1; off >>= 1) {
            s  += __shfl_xor(s, off, 64);
            s2 += __shfl_xor(s2, off, 64);
        }
        const float mean = s * (1.0f / 128.0f);
        const float var = s2 * (1.0f / 128.0f) - mean * mean;
        const float rstd = rsqrtf(var + 1e-5f);
        float* dst = tri_out + (size_t)((b * 128 + jf) * 128 + kf) * 128;
        dst[l]      = (v0 - mean) * rstd * sc0 + bi0;
        dst[l + 64] = (v1 - mean) * rstd * sc1 + bi1;
    }
}

// ---------------------------------------------------------------------------
extern "C" void kernel_launch(void* const* d_in, const int* in_sizes, int n_in,
                              void* d_out, int out_size, void* d_ws, size_t ws_size,
                              hipStream_t stream) {
    const float* node_fts  = (const float*)d_in[0];
    const float* edge_fts  = (const float*)d_in[1];
    const float* graph_fts = (const float*)d_in[2];
    const float* hidden    = (const float*)d_in[3];
    const int*   adj       = (const int*)d_in[4];
    const float* m1_w = (const float*)d_in[5],  *m1_b = (const float*)d_in[6];
    const float* m2_w = (const float*)d_in[7],  *m2_b = (const float*)d_in[8];
    const float* me_w = (const float*)d_in[9],  *me_b = (const float*)d_in[10];
    const float* mg_w = (const float*)d_in[11], *mg_b = (const float*)d_in[12];
    const float* mlp1_w = (const float*)d_in[13], *mlp1_b = (const float*)d_in[14];
    const float* mlp2_w = (const float*)d_in[15], *mlp2_b = (const float*)d_in[16];
    const float* o1_w = (const float*)d_in[17], *o1_b = (const float*)d_in[18];
    const float* o2_w = (const float*)d_in[19], *o2_b = (const float*)d_in[20];
    const float* t1_w = (const float*)d_in[21], *t1_b = (const float*)d_in[22];
    const float* t2_w = (const float*)d_in[23], *t2_b = (const float*)d_in[24];
    const float* te1_w = (const float*)d_in[25], *te1_b = (const float*)d_in[26];
    const float* te2_w = (const float*)d_in[27], *te2_b = (const float*)d_in[28];
    const float* te3_w = (const float*)d_in[29], *te3_b = (const float*)d_in[30];
    const float* tg_w = (const float*)d_in[31], *tg_b = (const float*)d_in[32];
    const float* o3_w = (const float*)d_in[33], *o3_b = (const float*)d_in[34];
    const float* norm_scale = (const float*)d_in[35];
    const float* norm_bias  = (const float*)d_in[36];

    char* w8 = (char*)d_ws;
    float*    M1    = (float*)(w8 + 0);          // 256 KB
    float*    M2    = (float*)(w8 + 262144);     // 256 KB
    float*    O1z   = (float*)(w8 + 524288);     // 256 KB
    float*    T1v   = (float*)(w8 + 786432);     // 16 KB
    float*    TT2   = (float*)(w8 + 802816);     // 16 KB
    ushort_t* Wme   = (ushort_t*)(w8 + 819200);  // 32 KB
    ushort_t* Wm1   = (ushort_t*)(w8 + 851968);  // 32 KB
    ushort_t* Wm2   = (ushort_t*)(w8 + 884736);  // 32 KB
    ushort_t* TEt   = (ushort_t*)(w8 + 917504);  // 8 KB
    ushort_t* msgsM = (ushort_t*)(w8 + 925696);  // 16 MB
    float*    T1buf = (float*)(w8 + 17702912);   // 2 MB
    float*    T2buf = (float*)(w8 + 19800064);   // 2 MB
    float*    E3buf = (float*)(w8 + 21897216);   // 2 MB
    ushort_t* Wnt   = (ushort_t*)(w8 + 23994368);// 208 KB
    float*    G1    = (float*)(w8 + 24207360);   // 2 KB
    float*    TG    = (float*)(w8 + 24209408);   // 128 B

    float* out_p  = (float*)d_out;            // [4,128,128]
    float* tri_p  = (float*)d_out + 65536;    // [4,128,128,128]

    prep_kernel<<<627, 256, 0, stream>>>(m1_w, m2_w, o1_w, t1_w, t2_w,
                                         me_w, mlp1_w, mlp2_w, te1_w, te2_w, te3_w,
                                         graph_fts, mg_w, mg_b, m1_b, tg_w, t2_b, tg_b,
                                         Wnt, Wme, Wm1, Wm2, TEt, G1, TG);
    node_gemm<<<16, 256, 0, stream>>>(node_fts, hidden, Wnt, G1, m2_b, o1_b, t1_b, TG,
                                      M1, M2, O1z, T1v, TT2);
    edge_kernel<<<512, 256, 0, stream>>>(edge_fts, Wme, me_b, Wm1, mlp1_b, Wm2, mlp2_b,
                                         TEt, te1_b, te2_b, te3_b,
                                         M1, M2, T1v, TT2, msgsM, T1buf, T2buf, E3buf);
    agg_out_kernel<<<512, 256, 0, stream>>>(msgsM, adj, O1z, o2_w, o2_b,
                                            norm_scale, norm_bias, out_p);
    tri_kernel<<<256, 256, 0, stream>>>(T1buf, T2buf, E3buf, o3_w, o3_b,
                                        norm_scale, norm_bias, tri_p);
}

// Round 5
// 111.257 us; speedup vs baseline: 2.1838x; 1.1527x over previous
//
#include <hip/hip_runtime.h>
#include <hip/hip_bf16.h>
#include <cstddef>
#include <cstdint>

typedef __attribute__((ext_vector_type(8))) short bf16x8;
typedef __attribute__((ext_vector_type(4))) float f32x4;
typedef unsigned short ushort_t;

__device__ __forceinline__ ushort_t f2b(float f) {
    uint32_t x = __float_as_uint(f);
    uint32_t r = (x + 0x7FFFu + ((x >> 16) & 1u)) >> 16;   // RNE
    return (ushort_t)r;
}
__device__ __forceinline__ float b2f(ushort_t u) {
    return __uint_as_float(((uint32_t)u) << 16);
}

// ---------------------------------------------------------------------------
// prep: build all bf16-transposed weights + folded graph biases.
// ---------------------------------------------------------------------------
__global__ void prep_kernel(const float* __restrict__ m1_w, const float* __restrict__ m2_w,
                            const float* __restrict__ o1_w, const float* __restrict__ t1_w,
                            const float* __restrict__ t2_w,
                            const float* __restrict__ me_w, const float* __restrict__ mlp1_w,
                            const float* __restrict__ mlp2_w,
                            const float* __restrict__ te1_w, const float* __restrict__ te2_w,
                            const float* __restrict__ te3_w,
                            const float* __restrict__ graph_fts,
                            const float* __restrict__ mg_w, const float* __restrict__ mg_b,
                            const float* __restrict__ m1_b,
                            const float* __restrict__ tg_w, const float* __restrict__ t2_b,
                            const float* __restrict__ tg_b,
                            ushort_t* __restrict__ Wnt,
                            ushort_t* __restrict__ Wme, ushort_t* __restrict__ Wm1,
                            ushort_t* __restrict__ Wm2, ushort_t* __restrict__ TEt,
                            float* __restrict__ G1, float* __restrict__ TG) {
    int idx = blockIdx.x * 256 + threadIdx.x;
    if (idx < 106496) {                       // Wnt: o*256 + k
        int o = idx >> 8, k = idx & 255;
        float v = 0.0f;
        if (o < 128)       v = m1_w[k * 128 + o];
        else if (o < 256)  v = m2_w[k * 128 + (o - 128)];
        else if (o < 384)  v = o1_w[k * 128 + (o - 256)];
        else if (o < 392)  v = t1_w[k * 8 + (o - 384)];
        else if (o < 400)  v = t2_w[k * 8 + (o - 392)];
        Wnt[idx] = f2b(v);
    } else if (idx < 122880) {
        int t = idx - 106496, o = t >> 7, h = t & 127;
        Wme[t] = f2b(me_w[h * 128 + o]);
    } else if (idx < 139264) {
        int t = idx - 122880, o = t >> 7, h = t & 127;
        Wm1[t] = f2b(mlp1_w[h * 128 + o]);
    } else if (idx < 155648) {
        int t = idx - 139264, o = t >> 7, h = t & 127;
        Wm2[t] = f2b(mlp2_w[h * 128 + o]);
    } else if (idx < 159744) {
        int t = idx - 155648, c = t >> 7, h = t & 127;
        float v = 0.0f;
        if (c < 8)       v = te1_w[h * 8 + c];
        else if (c < 16) v = te2_w[h * 8 + (c - 8)];
        else if (c < 24) v = te3_w[h * 8 + (c - 16)];
        TEt[t] = f2b(v);
    } else if (idx < 160256) {                // G1
        int t = idx - 159744, b = t >> 7, h = t & 127;
        float a = m1_b[h] + mg_b[h];
        #pragma unroll 4
        for (int k = 0; k < 128; k++) a = fmaf(graph_fts[b * 128 + k], mg_w[k * 128 + h], a);
        G1[t] = a;
    } else if (idx < 160288) {                // TG
        int t = idx - 160256, b = t >> 3, tt = t & 7;
        float a = t2_b[tt] + tg_b[tt];
        #pragma unroll 4
        for (int k = 0; k < 128; k++) a = fmaf(graph_fts[b * 128 + k], tg_w[k * 8 + tt], a);
        TG[t] = a;
    }
}

// ---------------------------------------------------------------------------
// node GEMM (MFMA bf16): Z[512x256] @ Wnt^T -> {M1,M2,O1z,T1v,TT2}
// ---------------------------------------------------------------------------
__global__ __launch_bounds__(256)
void node_gemm(const float* __restrict__ node_fts, const float* __restrict__ hidden,
               const ushort_t* __restrict__ Wnt,
               const float* __restrict__ G1, const float* __restrict__ m2_b,
               const float* __restrict__ o1_b, const float* __restrict__ t1_b,
               const float* __restrict__ TG,
               float* __restrict__ M1, float* __restrict__ M2, float* __restrict__ O1z,
               float* __restrict__ T1v, float* __restrict__ TT2) {
    __shared__ ushort_t Zs[32 * 256];         // 16 KB, swizzled
    char* Zb = (char*)Zs;
    const int tid = threadIdx.x;
    const int blk = blockIdx.x;               // 16 blocks
    const int b = blk >> 2, q = blk & 3;
    const int row0 = b * 128 + q * 32;
    const int w = tid >> 6, l = tid & 63, g = l >> 4, lq = l & 15;

    const float4* nsrc = reinterpret_cast<const float4*>(node_fts + (size_t)row0 * 128);
    const float4* hsrc = reinterpret_cast<const float4*>(hidden + (size_t)row0 * 128);
    #pragma unroll
    for (int p = 0; p < 8; p++) {
        int idx = tid + p * 256;
        int r = idx >> 6, c4 = idx & 63;
        float4 v = (c4 < 32) ? nsrc[r * 32 + c4] : hsrc[r * 32 + (c4 - 32)];
        uint2 pk;
        pk.x = (uint32_t)f2b(v.x) | ((uint32_t)f2b(v.y) << 16);
        pk.y = (uint32_t)f2b(v.z) | ((uint32_t)f2b(v.w) << 16);
        *reinterpret_cast<uint2*>(Zb + r * 512 + (((c4 >> 1) ^ (r & 7)) << 4) + (c4 & 1) * 8) = pk;
    }
    __syncthreads();

    for (int mt = w; mt < 26; mt += 4) {
        f32x4 acc0 = (f32x4){0.f, 0.f, 0.f, 0.f};
        f32x4 acc1 = (f32x4){0.f, 0.f, 0.f, 0.f};
        const ushort_t* arow = Wnt + (size_t)(mt * 16 + lq) * 256;
        #pragma unroll
        for (int ks = 0; ks < 8; ks++) {
            bf16x8 a = *reinterpret_cast<const bf16x8*>(arow + ks * 32 + g * 8);
            int j0 = lq, j1 = 16 + lq;
            bf16x8 b0 = *reinterpret_cast<const bf16x8*>(Zb + j0 * 512 + (((ks * 4 + g) ^ (j0 & 7)) << 4));
            bf16x8 b1 = *reinterpret_cast<const bf16x8*>(Zb + j1 * 512 + (((ks * 4 + g) ^ (j1 & 7)) << 4));
            acc0 = __builtin_amdgcn_mfma_f32_16x16x32_bf16(a, b0, acc0, 0, 0, 0);
            acc1 = __builtin_amdgcn_mfma_f32_16x16x32_bf16(a, b1, acc1, 0, 0, 0);
        }
        #pragma unroll
        for (int half = 0; half < 2; half++) {
            const f32x4 acc = half ? acc1 : acc0;
            const int grow = row0 + half * 16 + lq;
            #pragma unroll
            for (int c = 0; c < 4; c++) {
                int o = mt * 16 + g * 4 + c;
                float v = acc[c];
                if (o < 128)       M1[(size_t)grow * 128 + o] = v + G1[b * 128 + o];
                else if (o < 256)  M2[(size_t)grow * 128 + (o - 128)] = v + m2_b[o - 128];
                else if (o < 384)  O1z[(size_t)grow * 128 + (o - 256)] = v + o1_b[o - 256];
                else if (o < 392)  T1v[(size_t)grow * 8 + (o - 384)] = v + t1_b[o - 384];
                else if (o < 400)  TT2[(size_t)grow * 8 + (o - 392)] = v + TG[b * 8 + (o - 392)];
            }
        }
    }
}

// ---------------------------------------------------------------------------
// edge kernel, MFMA bf16 (unchanged from R3)
// ---------------------------------------------------------------------------
__device__ __forceinline__ void mm128(const ushort_t* __restrict__ Wt, const char* Xb,
                                      f32x4 acc[4][4], int o_blk, int j_blk, int g, int lq) {
    #pragma unroll
    for (int ks = 0; ks < 4; ks++) {
        bf16x8 a[4], bb[4];
        #pragma unroll
        for (int m = 0; m < 4; m++)
            a[m] = *reinterpret_cast<const bf16x8*>(Wt + (size_t)(o_blk + m * 16 + lq) * 128 + ks * 32 + g * 8);
        #pragma unroll
        for (int n = 0; n < 4; n++) {
            int j = j_blk + n * 16 + lq;
            bb[n] = *reinterpret_cast<const bf16x8*>(Xb + j * 256 + (((ks * 4 + g) ^ (j & 7)) << 4));
        }
        #pragma unroll
        for (int m = 0; m < 4; m++)
            #pragma unroll
            for (int n = 0; n < 4; n++)
                acc[m][n] = __builtin_amdgcn_mfma_f32_16x16x32_bf16(a[m], bb[n], acc[m][n], 0, 0, 0);
    }
}

__global__ __launch_bounds__(256, 2)
void edge_kernel(const float* __restrict__ edge_fts,
                 const ushort_t* __restrict__ Wme, const float* __restrict__ me_b,
                 const ushort_t* __restrict__ Wm1, const float* __restrict__ mlp1_b,
                 const ushort_t* __restrict__ Wm2, const float* __restrict__ mlp2_b,
                 const ushort_t* __restrict__ TEt,
                 const float* __restrict__ te1_b, const float* __restrict__ te2_b,
                 const float* __restrict__ te3_b,
                 const float* __restrict__ M1,  const float* __restrict__ M2,
                 const float* __restrict__ T1v, const float* __restrict__ TT2,
                 ushort_t* __restrict__ msgsM, float* __restrict__ T1buf,
                 float* __restrict__ T2buf, float* __restrict__ E3buf) {
    __shared__ ushort_t Xs[16384];     // 32 KB bf16 tile, swizzled
    char* Xb = (char*)Xs;
    const int tid = threadIdx.x;
    const int b  = blockIdx.x >> 7;
    const int ie = blockIdx.x & 127;
    const int w = tid >> 6, l = tid & 63, g = l >> 4, lq = l & 15;
    const int o_blk = (w & 1) * 64, j_blk = (w >> 1) * 64;

    // ---- stage 0: global fp32 -> bf16 swizzled LDS ----
    const float4* esrc = reinterpret_cast<const float4*>(edge_fts + (size_t)(b * 128 + ie) * 16384);
    #pragma unroll
    for (int p = 0; p < 16; p++) {
        int idx = tid + p * 256;
        int r = idx >> 5, c4 = idx & 31;
        float4 v = esrc[idx];
        uint2 pk;
        pk.x = (uint32_t)f2b(v.x) | ((uint32_t)f2b(v.y) << 16);
        pk.y = (uint32_t)f2b(v.z) | ((uint32_t)f2b(v.w) << 16);
        *reinterpret_cast<uint2*>(Xb + r * 256 + (((c4 >> 1) ^ (r & 7)) << 4) + (c4 & 1) * 8) = pk;
    }
    __syncthreads();

    // ---- te projections ----
    {
        const int m_te = w & 1;
        const ushort_t* At = TEt + m_te * 16 * 128;
        f32x4 acc[4];
        #pragma unroll
        for (int n = 0; n < 4; n++) acc[n] = (f32x4){0.f, 0.f, 0.f, 0.f};
        #pragma unroll
        for (int ks = 0; ks < 4; ks++) {
            bf16x8 a = *reinterpret_cast<const bf16x8*>(At + lq * 128 + ks * 32 + g * 8);
            #pragma unroll
            for (int n = 0; n < 4; n++) {
                int j = j_blk + n * 16 + lq;
                bf16x8 bbv = *reinterpret_cast<const bf16x8*>(Xb + j * 256 + (((ks * 4 + g) ^ (j & 7)) << 4));
                acc[n] = __builtin_amdgcn_mfma_f32_16x16x32_bf16(a, bbv, acc[n], 0, 0, 0);
            }
        }
        if (m_te == 0) {
            if (g < 2) {   // te1: T1buf[b][j][ie][t]
                int t0 = g * 4;
                const float4 eb = *reinterpret_cast<const float4*>(te1_b + t0);
                const float4 tv = *reinterpret_cast<const float4*>(T1v + (size_t)(b * 128 + ie) * 8 + t0);
                #pragma unroll
                for (int n = 0; n < 4; n++) {
                    int j = j_blk + n * 16 + lq;
                    float4 o4 = make_float4(acc[n][0] + eb.x + tv.x, acc[n][1] + eb.y + tv.y,
                                            acc[n][2] + eb.z + tv.z, acc[n][3] + eb.w + tv.w);
                    *reinterpret_cast<float4*>(T1buf + ((size_t)(b * 128 + j) * 128 + ie) * 8 + t0) = o4;
                }
            } else {       // te2: T2buf[b][ie][j][t]
                int t0 = g * 4 - 8;
                const float4 eb = *reinterpret_cast<const float4*>(te2_b + t0);
                #pragma unroll
                for (int n = 0; n < 4; n++) {
                    int j = j_blk + n * 16 + lq;
                    float4 o4 = make_float4(acc[n][0] + eb.x, acc[n][1] + eb.y,
                                            acc[n][2] + eb.z, acc[n][3] + eb.w);
                    *reinterpret_cast<float4*>(T2buf + ((size_t)(b * 128 + ie) * 128 + j) * 8 + t0) = o4;
                }
            }
        } else if (g < 2) { // te3: E3buf[b][ie][j][t] + TT2[b,ie] + T1v[b,j]
            int t0 = g * 4;
            const float4 eb = *reinterpret_cast<const float4*>(te3_b + t0);
            const float4 t2v = *reinterpret_cast<const float4*>(TT2 + (size_t)(b * 128 + ie) * 8 + t0);
            #pragma unroll
            for (int n = 0; n < 4; n++) {
                int j = j_blk + n * 16 + lq;
                const float4 t3v = *reinterpret_cast<const float4*>(T1v + (size_t)(b * 128 + j) * 8 + t0);
                float4 o4 = make_float4(acc[n][0] + eb.x + t2v.x + t3v.x,
                                        acc[n][1] + eb.y + t2v.y + t3v.y,
                                        acc[n][2] + eb.z + t2v.z + t3v.z,
                                        acc[n][3] + eb.w + t2v.w + t3v.w);
                *reinterpret_cast<float4*>(E3buf + ((size_t)(b * 128 + ie) * 128 + j) * 8 + t0) = o4;
            }
        }
    }

    f32x4 acc[4][4];

    // ================= stage 1 =================
    #pragma unroll
    for (int m = 0; m < 4; m++)
        #pragma unroll
        for (int n = 0; n < 4; n++) acc[m][n] = (f32x4){0.f, 0.f, 0.f, 0.f};
    mm128(Wme, Xb, acc, o_blk, j_blk, g, lq);
    {
        float4 bc[4];
        #pragma unroll
        for (int m = 0; m < 4; m++) {
            int o0 = o_blk + m * 16 + g * 4;
            const float4 eb = *reinterpret_cast<const float4*>(me_b + o0);
            const float4 m2 = *reinterpret_cast<const float4*>(M2 + (size_t)(b * 128 + ie) * 128 + o0);
            bc[m] = make_float4(eb.x + m2.x, eb.y + m2.y, eb.z + m2.z, eb.w + m2.w);
        }
        __syncthreads();
        #pragma unroll
        for (int m = 0; m < 4; m++) {
            int o0 = o_blk + m * 16 + g * 4;
            #pragma unroll
            for (int n = 0; n < 4; n++) {
                int j = j_blk + n * 16 + lq;
                const float4 m1 = *reinterpret_cast<const float4*>(M1 + (size_t)(b * 128 + j) * 128 + o0);
                float r0 = fmaxf(acc[m][n][0] + bc[m].x + m1.x, 0.f);
                float r1 = fmaxf(acc[m][n][1] + bc[m].y + m1.y, 0.f);
                float r2 = fmaxf(acc[m][n][2] + bc[m].z + m1.z, 0.f);
                float r3 = fmaxf(acc[m][n][3] + bc[m].w + m1.w, 0.f);
                uint2 pk;
                pk.x = (uint32_t)f2b(r0) | ((uint32_t)f2b(r1) << 16);
                pk.y = (uint32_t)f2b(r2) | ((uint32_t)f2b(r3) << 16);
                *reinterpret_cast<uint2*>(Xb + j * 256 + ((((o0 >> 3) ^ (j & 7))) << 4) + (o0 & 7) * 2) = pk;
            }
        }
        __syncthreads();
    }

    // ================= stage 2 =================
    #pragma unroll
    for (int m = 0; m < 4; m++)
        #pragma unroll
        for (int n = 0; n < 4; n++) acc[m][n] = (f32x4){0.f, 0.f, 0.f, 0.f};
    mm128(Wm1, Xb, acc, o_blk, j_blk, g, lq);
    {
        float4 bc[4];
        #pragma unroll
        for (int m = 0; m < 4; m++) {
            int o0 = o_blk + m * 16 + g * 4;
            bc[m] = *reinterpret_cast<const float4*>(mlp1_b + o0);
        }
        __syncthreads();
        #pragma unroll
        for (int m = 0; m < 4; m++) {
            int o0 = o_blk + m * 16 + g * 4;
            #pragma unroll
            for (int n = 0; n < 4; n++) {
                int j = j_blk + n * 16 + lq;
                float r0 = fmaxf(acc[m][n][0] + bc[m].x, 0.f);
                float r1 = fmaxf(acc[m][n][1] + bc[m].y, 0.f);
                float r2 = fmaxf(acc[m][n][2] + bc[m].z, 0.f);
                float r3 = fmaxf(acc[m][n][3] + bc[m].w, 0.f);
                uint2 pk;
                pk.x = (uint32_t)f2b(r0) | ((uint32_t)f2b(r1) << 16);
                pk.y = (uint32_t)f2b(r2) | ((uint32_t)f2b(r3) << 16);
                *reinterpret_cast<uint2*>(Xb + j * 256 + ((((o0 >> 3) ^ (j & 7))) << 4) + (o0 & 7) * 2) = pk;
            }
        }
        __syncthreads();
    }

    // ================= stage 3 =================
    #pragma unroll
    for (int m = 0; m < 4; m++)
        #pragma unroll
        for (int n = 0; n < 4; n++) acc[m][n] = (f32x4){0.f, 0.f, 0.f, 0.f};
    mm128(Wm2, Xb, acc, o_blk, j_blk, g, lq);
    {
        float4 bc[4];
        #pragma unroll
        for (int m = 0; m < 4; m++) {
            int o0 = o_blk + m * 16 + g * 4;
            bc[m] = *reinterpret_cast<const float4*>(mlp2_b + o0);
        }
        __syncthreads();
        #pragma unroll
        for (int m = 0; m < 4; m++) {
            int o0 = o_blk + m * 16 + g * 4;
            #pragma unroll
            for (int n = 0; n < 4; n++) {
                int j = j_blk + n * 16 + lq;
                float r0 = acc[m][n][0] + bc[m].x;
                float r1 = acc[m][n][1] + bc[m].y;
                float r2 = acc[m][n][2] + bc[m].z;
                float r3 = acc[m][n][3] + bc[m].w;
                uint2 pk;
                pk.x = (uint32_t)f2b(r0) | ((uint32_t)f2b(r1) << 16);
                pk.y = (uint32_t)f2b(r2) | ((uint32_t)f2b(r3) << 16);
                *reinterpret_cast<uint2*>(Xb + j * 256 + ((((o0 >> 3) ^ (j & 7))) << 4) + (o0 & 7) * 2) = pk;
            }
        }
        __syncthreads();
    }

    // ---- de-swizzle copy-out, transposed layout: msgsM[b][j=r][i=ie][h] ----
    {
        const int r0 = tid >> 4, sc = tid & 15;
        #pragma unroll
        for (int q = 0; q < 8; q++) {
            int r = r0 + q * 16;
            uint4 v = *reinterpret_cast<const uint4*>(Xb + r * 256 + sc * 16);
            int logical = sc ^ (r & 7);
            *reinterpret_cast<uint4*>(msgsM + ((size_t)(b * 128 + r) * 128 + ie) * 128 + logical * 8) = v;
        }
    }
}

// ---------------------------------------------------------------------------
// masked max aggregation (msgsM[b][j][i][h] bf16, contiguous per (b,j)) + head
// ---------------------------------------------------------------------------
__global__ __launch_bounds__(256)
void agg_out_kernel(const ushort_t* __restrict__ msgsM, const int* __restrict__ adj,
                    const float* __restrict__ O1z,
                    const float* __restrict__ o2_w, const float* __restrict__ o2_b,
                    const float* __restrict__ scale, const float* __restrict__ bias,
                    float* __restrict__ out) {
    __shared__ float aggs[4][128];
    __shared__ float fagg[128];
    __shared__ float red[2][2];
    const int b = blockIdx.x >> 7, j = blockIdx.x & 127;
    const int t = threadIdx.x;
    const int wv = t >> 6, ln = t & 63;
    const ushort_t* msrc = msgsM + (size_t)(b * 128 + j) * 16384;
    const int* arow = adj + b * 16384 + j;
    float a0 = -1e9f, a1 = -1e9f;
    #pragma unroll 8
    for (int s = 0; s < 32; s++) {
        const int i = s * 4 + wv;
        uint32_t u = *reinterpret_cast<const uint32_t*>(msrc + i * 128 + ln * 2);
        bool m = (arow[i * 128] == 1);
        float x0 = b2f((ushort_t)(u & 0xffffu));
        float x1 = b2f((ushort_t)(u >> 16));
        a0 = m ? fmaxf(a0, x0) : a0;
        a1 = m ? fmaxf(a1, x1) : a1;
    }
    aggs[wv][ln * 2]     = a0;
    aggs[wv][ln * 2 + 1] = a1;
    __syncthreads();
    if (t < 128)
        fagg[t] = fmaxf(fmaxf(aggs[0][t], aggs[1][t]), fmaxf(aggs[2][t], aggs[3][t]));
    __syncthreads();

    float v = 0.0f;
    if (t < 128) {
        float val = o2_b[t] + O1z[(size_t)(b * 128 + j) * 128 + t];
        #pragma unroll 4
        for (int k = 0; k < 128; k++) val = fmaf(fagg[k], o2_w[k * 128 + t], val);
        v = fmaxf(val, 0.0f);
    }
    float s = v, s2 = v * v;
    #pragma unroll
    for (int off = 32; off >= 1; off >>= 1) {
        s += __shfl_down(s, off, 64);
        s2 += __shfl_down(s2, off, 64);
    }
    if (t < 128 && (t & 63) == 0) { red[t >> 6][0] = s; red[t >> 6][1] = s2; }
    __syncthreads();
    if (t < 128) {
        const float tot = red[0][0] + red[1][0];
        const float tot2 = red[0][1] + red[1][1];
        const float mean = tot * (1.0f / 128.0f);
        const float var = tot2 * (1.0f / 128.0f) - mean * mean;
        const float rstd = rsqrtf(var + 1e-5f);
        out[(size_t)(b * 128 + j) * 128 + t] = (v - mean) * rstd * scale[t] + bias[t];
    }
}

// ---------------------------------------------------------------------------
// triplet kernel: 1 jf per block, 512 threads (8 waves).
// phase1: i split 4 ways -> Ps[4][128][8]; phase2: 8 waves x 16 kf rows.
// ---------------------------------------------------------------------------
__global__ __launch_bounds__(512)
void tri_kernel(const float* __restrict__ T1buf, const float* __restrict__ T2buf,
                const float* __restrict__ E3buf, const float* __restrict__ o3_w,
                const float* __restrict__ o3_b, const float* __restrict__ scale,
                const float* __restrict__ bias, float* __restrict__ tri_out) {
    __shared__ __align__(16) float T1s[1024];
    __shared__ __align__(16) float E3s[1024];
    __shared__ __align__(16) float o3s[1024];
    __shared__ __align__(16) float Ps[4][128][8];
    const int b = blockIdx.x >> 7, jf = blockIdx.x & 127;
    const int tid = threadIdx.x;
    if (tid < 256) {
        reinterpret_cast<float4*>(T1s)[tid] =
            reinterpret_cast<const float4*>(T1buf + (size_t)(b * 128 + jf) * 1024)[tid];
        reinterpret_cast<float4*>(o3s)[tid] = reinterpret_cast<const float4*>(o3_w)[tid];
    } else {
        int t2 = tid - 256;
        reinterpret_cast<float4*>(E3s)[t2] =
            reinterpret_cast<const float4*>(E3buf + (size_t)(b * 128 + jf) * 1024)[t2];
    }
    __syncthreads();

    {
        const int kf = tid & 127, ih = tid >> 7;      // ih 0..3
        float a8[8];
        #pragma unroll
        for (int t = 0; t < 8; t++) a8[t] = -3.0e38f;
        const float4* t2p = reinterpret_cast<const float4*>(T2buf + (size_t)b * 131072);
        #pragma unroll 4
        for (int ii = 0; ii < 32; ++ii) {
            const int i = ih * 32 + ii;
            const float4 p = t2p[(i * 128 + kf) * 2];
            const float4 q = t2p[(i * 128 + kf) * 2 + 1];
            const float* t1r = &T1s[i * 8];
            a8[0] = fmaxf(a8[0], t1r[0] + p.x);
            a8[1] = fmaxf(a8[1], t1r[1] + p.y);
            a8[2] = fmaxf(a8[2], t1r[2] + p.z);
            a8[3] = fmaxf(a8[3], t1r[3] + p.w);
            a8[4] = fmaxf(a8[4], t1r[4] + q.x);
            a8[5] = fmaxf(a8[5], t1r[5] + q.y);
            a8[6] = fmaxf(a8[6], t1r[6] + q.z);
            a8[7] = fmaxf(a8[7], t1r[7] + q.w);
        }
        #pragma unroll
        for (int t = 0; t < 8; t++) Ps[ih][kf][t] = a8[t];
    }
    __syncthreads();

    const int w = tid >> 6, l = tid & 63;
    const float ob0 = o3_b[l],     ob1 = o3_b[l + 64];
    const float sc0 = scale[l],    sc1 = scale[l + 64];
    const float bi0 = bias[l],     bi1 = bias[l + 64];
    for (int kk = 0; kk < 16; ++kk) {
        const int kf = w * 16 + kk;
        float m8[8];
        #pragma unroll
        for (int t = 0; t < 8; t++)
            m8[t] = fmaxf(fmaxf(Ps[0][kf][t], Ps[1][kf][t]),
                          fmaxf(Ps[2][kf][t], Ps[3][kf][t])) + E3s[kf * 8 + t];
        float v0 = ob0, v1 = ob1;
        #pragma unroll
        for (int t = 0; t < 8; t++) {
            v0 = fmaf(m8[t], o3s[t * 128 + l], v0);
            v1 = fmaf(m8[t], o3s[t * 128 + l + 64], v1);
        }
        v0 = fmaxf(v0, 0.0f);
        v1 = fmaxf(v1, 0.0f);
        float s = v0 + v1, s2 = v0 * v0 + v1 * v1;
        #pragma unroll
        for (int off = 32; off >= 1; off >>= 1) {
            s  += __shfl_xor(s, off, 64);
            s2 += __shfl_xor(s2, off, 64);
        }
        const float mean = s * (1.0f / 128.0f);
        const float var = s2 * (1.0f / 128.0f) - mean * mean;
        const float rstd = rsqrtf(var + 1e-5f);
        float* dst = tri_out + (size_t)((b * 128 + jf) * 128 + kf) * 128;
        dst[l]      = (v0 - mean) * rstd * sc0 + bi0;
        dst[l + 64] = (v1 - mean) * rstd * sc1 + bi1;
    }
}

// ---------------------------------------------------------------------------
extern "C" void kernel_launch(void* const* d_in, const int* in_sizes, int n_in,
                              void* d_out, int out_size, void* d_ws, size_t ws_size,
                              hipStream_t stream) {
    const float* node_fts  = (const float*)d_in[0];
    const float* edge_fts  = (const float*)d_in[1];
    const float* graph_fts = (const float*)d_in[2];
    const float* hidden    = (const float*)d_in[3];
    const int*   adj       = (const int*)d_in[4];
    const float* m1_w = (const float*)d_in[5],  *m1_b = (const float*)d_in[6];
    const float* m2_w = (const float*)d_in[7],  *m2_b = (const float*)d_in[8];
    const float* me_w = (const float*)d_in[9],  *me_b = (const float*)d_in[10];
    const float* mg_w = (const float*)d_in[11], *mg_b = (const float*)d_in[12];
    const float* mlp1_w = (const float*)d_in[13], *mlp1_b = (const float*)d_in[14];
    const float* mlp2_w = (const float*)d_in[15], *mlp2_b = (const float*)d_in[16];
    const float* o1_w = (const float*)d_in[17], *o1_b = (const float*)d_in[18];
    const float* o2_w = (const float*)d_in[19], *o2_b = (const float*)d_in[20];
    const float* t1_w = (const float*)d_in[21], *t1_b = (const float*)d_in[22];
    const float* t2_w = (const float*)d_in[23], *t2_b = (const float*)d_in[24];
    const float* te1_w = (const float*)d_in[25], *te1_b = (const float*)d_in[26];
    const float* te2_w = (const float*)d_in[27], *te2_b = (const float*)d_in[28];
    const float* te3_w = (const float*)d_in[29], *te3_b = (const float*)d_in[30];
    const float* tg_w = (const float*)d_in[31], *tg_b = (const float*)d_in[32];
    const float* o3_w = (const float*)d_in[33], *o3_b = (const float*)d_in[34];
    const float* norm_scale = (const float*)d_in[35];
    const float* norm_bias  = (const float*)d_in[36];

    char* w8 = (char*)d_ws;
    float*    M1    = (float*)(w8 + 0);          // 256 KB
    float*    M2    = (float*)(w8 + 262144);     // 256 KB
    float*    O1z   = (float*)(w8 + 524288);     // 256 KB
    float*    T1v   = (float*)(w8 + 786432);     // 16 KB
    float*    TT2   = (float*)(w8 + 802816);     // 16 KB
    ushort_t* Wme   = (ushort_t*)(w8 + 819200);  // 32 KB
    ushort_t* Wm1   = (ushort_t*)(w8 + 851968);  // 32 KB
    ushort_t* Wm2   = (ushort_t*)(w8 + 884736);  // 32 KB
    ushort_t* TEt   = (ushort_t*)(w8 + 917504);  // 8 KB
    ushort_t* msgsM = (ushort_t*)(w8 + 925696);  // 16 MB
    float*    T1buf = (float*)(w8 + 17702912);   // 2 MB
    float*    T2buf = (float*)(w8 + 19800064);   // 2 MB
    float*    E3buf = (float*)(w8 + 21897216);   // 2 MB
    ushort_t* Wnt   = (ushort_t*)(w8 + 23994368);// 208 KB
    float*    G1    = (float*)(w8 + 24207360);   // 2 KB
    float*    TG    = (float*)(w8 + 24209408);   // 128 B

    float* out_p  = (float*)d_out;            // [4,128,128]
    float* tri_p  = (float*)d_out + 65536;    // [4,128,128,128]

    prep_kernel<<<627, 256, 0, stream>>>(m1_w, m2_w, o1_w, t1_w, t2_w,
                                         me_w, mlp1_w, mlp2_w, te1_w, te2_w, te3_w,
                                         graph_fts, mg_w, mg_b, m1_b, tg_w, t2_b, tg_b,
                                         Wnt, Wme, Wm1, Wm2, TEt, G1, TG);
    node_gemm<<<16, 256, 0, stream>>>(node_fts, hidden, Wnt, G1, m2_b, o1_b, t1_b, TG,
                                      M1, M2, O1z, T1v, TT2);
    edge_kernel<<<512, 256, 0, stream>>>(edge_fts, Wme, me_b, Wm1, mlp1_b, Wm2, mlp2_b,
                                         TEt, te1_b, te2_b, te3_b,
                                         M1, M2, T1v, TT2, msgsM, T1buf, T2buf, E3buf);
    agg_out_kernel<<<512, 256, 0, stream>>>(msgsM, adj, O1z, o2_w, o2_b,
                                            norm_scale, norm_bias, out_p);
    tri_kernel<<<512, 512, 0, stream>>>(T1buf, T2buf, E3buf, o3_w, o3_b,
                                        norm_scale, norm_bias, tri_p);
}